// Round 16
// baseline (144.143 us; speedup 1.0000x reference)
//
#include <hip/hip_runtime.h>
#include <hip/hip_bf16.h>
#include <math.h>

#define S_ 2048

typedef __attribute__((ext_vector_type(8))) short bf16x8;
typedef __attribute__((ext_vector_type(4))) float f32x4;
typedef __attribute__((ext_vector_type(8))) unsigned short u16x8;
typedef __attribute__((ext_vector_type(4))) unsigned short u16x4;

__device__ inline unsigned short f2bf(float f) {
  union { float f; unsigned u; } x; x.f = f;
  unsigned r = x.u + 0x7fff + ((x.u >> 16) & 1);
  return (unsigned short)(r >> 16);
}

__device__ __forceinline__ float exp2_raw(float x) {
  float r;
  asm("v_exp_f32 %0, %1" : "=v"(r) : "v"(x));
  return r;
}

__device__ __forceinline__ void gll16(const unsigned short* g, unsigned short* l) {
  __builtin_amdgcn_global_load_lds(
      (const __attribute__((address_space(1))) unsigned int*)g,
      (__attribute__((address_space(3))) unsigned int*)l, 16, 0, 0);
}

// ---------------- fused prologue ----------------
__device__ __forceinline__ void transpose_tile(
    const float* __restrict__ in, unsigned short* __restrict__ out,
    int K, int N, int bx, int by, int tid, unsigned short (*tile)[72]) {
  const int k0 = by * 64, n0 = bx * 64;
  const int rr = tid >> 4, cc = (tid & 15) * 4;
#pragma unroll
  for (int p = 0; p < 4; ++p) {
    int k = rr + p * 16;
    float4 v = *(const float4*)&in[(size_t)(k0 + k) * N + n0 + cc];
    tile[k][cc + 0] = f2bf(v.x);
    tile[k][cc + 1] = f2bf(v.y);
    tile[k][cc + 2] = f2bf(v.z);
    tile[k][cc + 3] = f2bf(v.w);
  }
  __syncthreads();
#pragma unroll
  for (int p = 0; p < 4; ++p) {
    int n = rr + p * 16;
    u16x4 o;
    o[0] = tile[cc + 0][n];
    o[1] = tile[cc + 1][n];
    o[2] = tile[cc + 2][n];
    o[3] = tile[cc + 3][n];
    *(u16x4*)&out[(size_t)(n0 + n) * K + k0 + cc] = o;
  }
}

__global__ __launch_bounds__(256) void prologue_kernel(
    const float* __restrict__ hs, unsigned short* __restrict__ hsb,
    const float* __restrict__ w_qkv, unsigned short* __restrict__ wqT,
    const float* __restrict__ w_dense, unsigned short* __restrict__ wdT,
    const float* __restrict__ table, float* __restrict__ biasTab) {
  __shared__ unsigned short tile[64][72];
  const int blk = blockIdx.x;
  const int tid = threadIdx.x;
  if (blk < 2048) {
    int i = blk * 256 + tid;
    float4 a = ((const float4*)hs)[i * 2];
    float4 b = ((const float4*)hs)[i * 2 + 1];
    u16x8 o;
    o[0] = f2bf(a.x); o[1] = f2bf(a.y); o[2] = f2bf(a.z); o[3] = f2bf(a.w);
    o[4] = f2bf(b.x); o[5] = f2bf(b.y); o[6] = f2bf(b.z); o[7] = f2bf(b.w);
    *(u16x8*)&hsb[(size_t)i * 8] = o;
  } else if (blk < 2816) {
    int t = blk - 2048;
    transpose_tile(w_qkv, wqT, 1024, 3072, t % 48, t / 48, tid, tile);
  } else if (blk < 3072) {
    int t = blk - 2816;
    transpose_tile(w_dense, wdT, 1024, 1024, t % 16, t / 16, tid, tile);
  } else {
    int idx = (blk - 3072) * 256 + tid;
    int h = idx >> 12;
    int r = idx & 4095;
    int rel = r - 2047;
    int bucket = rel > 0 ? 16 : 0;
    int ar = rel < 0 ? -rel : rel;
    if (ar < 8) {
      bucket += ar;
    } else {
      float tmp = logf((float)ar / 8.0f);
      float lf = tmp / 2.7725887222397811f * 8.0f;
      int large = 8 + (int)lf;
      bucket += (large < 15 ? large : 15);
    }
    biasTab[idx] = table[h * 32 + bucket] * 1.44269504088896f;  // log2e domain
  }
}

// ------- bf16 MFMA GEMM, 128x128 tile, BK=64: C = A @ Bt^T + bias ------------
// XCD-swizzled. BF16OUT epilogue: Q/K repack->coalesced; V fused vperm -> vP.
template <bool BF16OUT>
__global__ __launch_bounds__(256) void gemm_mfma_kernel(
    const unsigned short* __restrict__ A, const unsigned short* __restrict__ Bt,
    const float* __restrict__ bias, void* __restrict__ Cout,
    unsigned short* __restrict__ vP, int M, int N, int K) {
  __shared__ __align__(16) unsigned short As[128 * 64];
  __shared__ __align__(16) unsigned short Bs[128 * 64];
  const int tid = threadIdx.x;
  const int wave = tid >> 6, lane = tid & 63;
  const int lg = lane >> 4, lr = lane & 15;
  const int nbx = gridDim.x;
  const int flat = blockIdx.y * nbx + blockIdx.x;
  const int cpx = (nbx * gridDim.y) >> 3;
  const int swzid = (flat & 7) * cpx + (flat >> 3);
  const int m0 = (swzid / nbx) * 128, n0 = (swzid % nbx) * 128;
  const int wm = (wave & 1) * 64, wn = (wave >> 1) * 64;

  f32x4 acc[4][4] = {};

  const int rbase = tid >> 3;
  const int lsw = ((tid & 7) ^ (rbase & 7)) * 8;
  const unsigned short* aP[4];
  const unsigned short* bP[4];
  unsigned short* ldsA[4];
  unsigned short* ldsB[4];
#pragma unroll
  for (int g = 0; g < 4; ++g) {
    aP[g] = A + (size_t)(m0 + g * 32 + rbase) * K + lsw;
    bP[g] = Bt + (size_t)(n0 + g * 32 + rbase) * K + lsw;
    ldsA[g] = &As[g * 2048 + (tid & ~63) * 8];
    ldsB[g] = &Bs[g * 2048 + (tid & ~63) * 8];
  }

  for (int kt = 0; kt < K; kt += 64) {
    __syncthreads();
#pragma unroll
    for (int g = 0; g < 4; ++g) {
      gll16(aP[g] + kt, ldsA[g]);
      gll16(bP[g] + kt, ldsB[g]);
    }
    __syncthreads();
#pragma unroll
    for (int kh = 0; kh < 2; ++kh) {
      bf16x8 af[4], bfr[4];
#pragma unroll
      for (int t = 0; t < 4; ++t) {
        const int slot = ((kh * 4 + lg) ^ (lr & 7)) * 8;
        af[t]  = *(const bf16x8*)&As[(wm + t * 16 + lr) * 64 + slot];
        bfr[t] = *(const bf16x8*)&Bs[(wn + t * 16 + lr) * 64 + slot];
      }
#pragma unroll
      for (int i = 0; i < 4; ++i)
#pragma unroll
        for (int j = 0; j < 4; ++j)
          acc[i][j] = __builtin_amdgcn_mfma_f32_16x16x32_bf16(
              af[i], bfr[j], acc[i][j], 0, 0, 0);
    }
  }

  float bv[4];
#pragma unroll
  for (int j = 0; j < 4; ++j) bv[j] = bias[n0 + wn + j * 16 + lr];

  if constexpr (BF16OUT) {
    __syncthreads();   // all waves' frag reads of As/Bs complete before reuse
    if (n0 < 2048) {
      unsigned short* rp = &As[wave * 1024];
#pragma unroll
      for (int i = 0; i < 4; ++i) {
#pragma unroll
        for (int j = 0; j < 4; ++j) {
          const int cw = ((j + lg) & 3) * 16 + lr;
#pragma unroll
          for (int r = 0; r < 4; ++r)
            rp[(lg * 4 + r) * 64 + cw] = f2bf(acc[i][j][r] + bv[j]);
        }
#pragma unroll
        for (int pass = 0; pass < 2; ++pass) {
          const int row = pass * 8 + (lane >> 3);
          const int cread = ((((lane & 7) >> 1) + (row >> 2)) & 3) * 16 +
                            (lane & 1) * 8;
          u16x8 v = *(const u16x8*)&rp[row * 64 + cread];
          *(u16x8*)&((unsigned short*)Cout)[
              (size_t)(m0 + wm + i * 16 + row) * N + n0 + wn + (lane & 7) * 8] = v;
        }
      }
    } else {
      // ---- V epilogue: fused vperm (64k x 64d per wave) ----
      unsigned short* R = (wave < 2) ? &As[(wave & 1) * 4096]
                                     : &Bs[(wave & 1) * 4096];
#pragma unroll
      for (int i = 0; i < 4; ++i) {
        const int lsv = (i >> 1) * 4 + lg;
        const int ebase = (i & 1) * 4;
#pragma unroll
        for (int j = 0; j < 4; ++j) {
          const int d = j * 16 + lr;
          const int ps = lsv ^ (d & 7);
          u16x4 o;
#pragma unroll
          for (int r = 0; r < 4; ++r) o[r] = f2bf(acc[i][j][r] + bv[j]);
          *(u16x4*)&R[d * 64 + ps * 8 + ebase] = o;
        }
      }
      const int krow0 = m0 + wm;
      const int bbv = krow0 >> 11;
      const int sbase = krow0 & 2047;
      const int h = ((n0 - 2048) >> 6) + (wave >> 1);
#pragma unroll
      for (int it = 0; it < 8; ++it) {
        const int d = it * 8 + (lane >> 3);
        const int c = lane & 7;
        u16x8 v = *(const u16x8*)&R[d * 64 + c * 8];
        *(u16x8*)&vP[((size_t)((bbv * 16 + h) * 64 + d)) * 2048 +
                     sbase + c * 8] = v;
      }
    }
  } else {
#pragma unroll
    for (int i = 0; i < 4; ++i)
#pragma unroll
      for (int j = 0; j < 4; ++j)
#pragma unroll
        for (int r = 0; r < 4; ++r) {
          int row = m0 + wm + i * 16 + lg * 4 + r;
          int col = n0 + wn + j * 16 + lr;
          ((float*)Cout)[(size_t)row * N + col] = acc[i][j][r] + bv[j];
        }
  }
}

// ------- bf16 MFMA GEMM, 64x128 tile, BK=64 (2x occupancy, small shapes) -----
template <bool BF16OUT>
__global__ __launch_bounds__(256) void gemm_mfma64_kernel(
    const unsigned short* __restrict__ A, const unsigned short* __restrict__ Bt,
    const float* __restrict__ bias, void* __restrict__ Cout,
    int M, int N, int K) {
  __shared__ __align__(16) unsigned short As[64 * 64];
  __shared__ __align__(16) unsigned short Bs[128 * 64];
  const int tid = threadIdx.x;
  const int wave = tid >> 6, lane = tid & 63;
  const int lg = lane >> 4, lr = lane & 15;
  const int nbx = gridDim.x;
  const int flat = blockIdx.y * nbx + blockIdx.x;
  const int cpx = (nbx * gridDim.y) >> 3;
  const int swzid = (flat & 7) * cpx + (flat >> 3);
  const int m0 = (swzid / nbx) * 64, n0 = (swzid % nbx) * 128;
  const int wm = (wave & 1) * 32, wn = (wave >> 1) * 64;

  f32x4 acc[2][4] = {};

  const int rbase = tid >> 3;
  const int lsw = ((tid & 7) ^ (rbase & 7)) * 8;
  const unsigned short* aP[2];
  const unsigned short* bP[4];
  unsigned short* ldsA[2];
  unsigned short* ldsB[4];
#pragma unroll
  for (int g = 0; g < 2; ++g) {
    aP[g] = A + (size_t)(m0 + g * 32 + rbase) * K + lsw;
    ldsA[g] = &As[g * 2048 + (tid & ~63) * 8];
  }
#pragma unroll
  for (int g = 0; g < 4; ++g) {
    bP[g] = Bt + (size_t)(n0 + g * 32 + rbase) * K + lsw;
    ldsB[g] = &Bs[g * 2048 + (tid & ~63) * 8];
  }

  for (int kt = 0; kt < K; kt += 64) {
    __syncthreads();
#pragma unroll
    for (int g = 0; g < 2; ++g) gll16(aP[g] + kt, ldsA[g]);
#pragma unroll
    for (int g = 0; g < 4; ++g) gll16(bP[g] + kt, ldsB[g]);
    __syncthreads();
#pragma unroll
    for (int kh = 0; kh < 2; ++kh) {
      bf16x8 af[2], bfr[4];
      const int slotb = ((kh * 4 + lg) ^ (lr & 7)) * 8;
#pragma unroll
      for (int t = 0; t < 2; ++t)
        af[t] = *(const bf16x8*)&As[(wm + t * 16 + lr) * 64 + slotb];
#pragma unroll
      for (int t = 0; t < 4; ++t)
        bfr[t] = *(const bf16x8*)&Bs[(wn + t * 16 + lr) * 64 + slotb];
#pragma unroll
      for (int i = 0; i < 2; ++i)
#pragma unroll
        for (int j = 0; j < 4; ++j)
          acc[i][j] = __builtin_amdgcn_mfma_f32_16x16x32_bf16(
              af[i], bfr[j], acc[i][j], 0, 0, 0);
    }
  }

  float bv[4];
#pragma unroll
  for (int j = 0; j < 4; ++j) bv[j] = bias[n0 + wn + j * 16 + lr];
#pragma unroll
  for (int i = 0; i < 2; ++i) {
#pragma unroll
    for (int j = 0; j < 4; ++j) {
#pragma unroll
      for (int r = 0; r < 4; ++r) {
        int row = m0 + wm + i * 16 + lg * 4 + r;
        int col = n0 + wn + j * 16 + lr;
        float val = acc[i][j][r] + bv[j];
        if constexpr (BF16OUT)
          ((unsigned short*)Cout)[(size_t)row * N + col] = f2bf(val);
        else
          ((float*)Cout)[(size_t)row * N + col] = val;
      }
    }
  }
}

// ---------------- bf16 MFMA flash attention v7: KVBLK=128 ----------------
// 8 waves x 16 q-rows, K-tile 128 -> 16 iters (half the barrier drains).
__global__ __launch_bounds__(512) void attn_mfma7_kernel(
    const unsigned short* __restrict__ qkvb, const unsigned short* __restrict__ vP,
    const float* __restrict__ biasTab, unsigned short* __restrict__ ctxb) {
  const int wg0 = blockIdx.x;
  const int wg = (wg0 & 7) * 64 + (wg0 >> 3);
  const int qt = wg & 15;
  const int h  = (wg >> 4) & 15;
  const int bb = wg >> 8;

  const int tid = threadIdx.x;
  const int wave = tid >> 6;
  const int lane = tid & 63;
  const int lg = lane >> 4;
  const int lr = lane & 15;

  __shared__ __align__(16) unsigned short Klds[2][8192];  // [128 k][8 slot][8]
  __shared__ __align__(16) unsigned short Vlds[2][8192];  // [64 d][2 sub][8 slot][8]
  __shared__ float biasW[2][256];

  const int q0 = qt * 128;
  const int qw = q0 + wave * 16;
  const float SCL = 0.125f * 1.44269504088896f;
  const float THR = 11.5415603f;

  bf16x8 qf[2];
#pragma unroll
  for (int kh = 0; kh < 2; ++kh)
    qf[kh] = *(const bf16x8*)(qkvb +
        (size_t)(bb * S_ + qw + lr) * 3072 + h * 64 + kh * 32 + lg * 8);

  float mrun = -1e30f;
  float lpart = 0.f;
  f32x4 ov[4] = {};

  // K chunk c=tid: k=tid>>3 (0..63), slot pb=tid&7; chunk tid+512: k+64, same pb
  const int kk = tid >> 3, kpb = tid & 7;
  const unsigned short* kptr = qkvb + (size_t)(bb * S_ + kk) * 3072 + 1024 +
                               h * 64 + (kpb ^ (kk & 7)) * 8;
  // V chunk c=tid: d=tid>>4 (0..31), mslot=tid&15; chunk tid+512: d+32
  const unsigned short* vptr = vP + ((size_t)((bb * 16 + h) * 64 + (tid >> 4))) * 2048 +
                               (tid & 15) * 8;
  const float* btabH = biasTab + h * 4096 + 2047;

  auto nonuni = [&](int tt) {
    int rl = tt * 128 - q0;
    return !((rl - 127 >= 91) || (rl + 127 <= -91));
  };

  // ---- prologue: stage tile 0 (128 k-rows) ----
  gll16(kptr, &Klds[0][(tid & ~63) * 8]);
  gll16(kptr + (size_t)64 * 3072, &Klds[0][4096 + (tid & ~63) * 8]);
  gll16(vptr, &Vlds[0][(tid & ~63) * 8]);
  gll16(vptr + (size_t)32 * 2048, &Vlds[0][4096 + (tid & ~63) * 8]);
  if (nonuni(0) && tid < 256) biasW[0][tid] = btabH[-q0 - 127 + tid];

  for (int t = 0; t < 16; ++t) {
    const int cur = t & 1;
    __syncthreads();   // drains gll16 (vmcnt) + bias writes; swaps buffers

    if (t < 15) {
      const size_t kadv = (size_t)(t + 1) * 128 * 3072;
      const int vadv = (t + 1) * 128;
      gll16(kptr + kadv, &Klds[cur ^ 1][(tid & ~63) * 8]);
      gll16(kptr + kadv + (size_t)64 * 3072, &Klds[cur ^ 1][4096 + (tid & ~63) * 8]);
      gll16(vptr + vadv, &Vlds[cur ^ 1][(tid & ~63) * 8]);
      gll16(vptr + vadv + (size_t)32 * 2048, &Vlds[cur ^ 1][4096 + (tid & ~63) * 8]);
      if (nonuni(t + 1) && tid < 256)
        biasW[cur ^ 1][tid] = btabH[(t + 1) * 128 - q0 - 127 + tid];
    }

    // ---- QK^T swapped: sc[kt][r] = S[kt*16+lg*4+r][qw+lr], kt=0..7 ----
    f32x4 sc[8] = {};
    __builtin_amdgcn_s_setprio(1);
#pragma unroll
    for (int kt = 0; kt < 8; ++kt) {
      const unsigned short* kr = &Klds[cur][(kt * 16 + lr) * 64];
      bf16x8 kf0 = *(const bf16x8*)(kr + ((lg)     ^ (lr & 7)) * 8);
      bf16x8 kf1 = *(const bf16x8*)(kr + ((4 + lg) ^ (lr & 7)) * 8);
      sc[kt] = __builtin_amdgcn_mfma_f32_16x16x32_bf16(kf0, qf[0], sc[kt], 0, 0, 0);
      sc[kt] = __builtin_amdgcn_mfma_f32_16x16x32_bf16(kf1, qf[1], sc[kt], 0, 0, 0);
    }
    __builtin_amdgcn_s_setprio(0);

    // ---- V fragments hoisted (16 b128; overlap with softmax VALU) ----
    bf16x8 vfr[4][4];
#pragma unroll
    for (int c = 0; c < 4; ++c)
#pragma unroll
      for (int db = 0; db < 4; ++db)
        vfr[c][db] = *(const bf16x8*)&Vlds[cur][
            (db * 16 + lr) * 128 + (c >> 1) * 64 +
            ((4 * (c & 1) + lg) ^ (lr & 7)) * 8];

    // ---- bias (log2e domain) ----
    float pp[8][4];
    if (nonuni(t)) {
      const int bidx = 127 + lg * 4 - wave * 16 - lr;
#pragma unroll
      for (int kt = 0; kt < 8; ++kt)
#pragma unroll
        for (int r = 0; r < 4; ++r)
          pp[kt][r] = sc[kt][r] * SCL + biasW[cur][bidx + kt * 16 + r];
    } else {
      const float cb = btabH[t * 128 - q0];
#pragma unroll
      for (int kt = 0; kt < 8; ++kt)
#pragma unroll
        for (int r = 0; r < 4; ++r)
          pp[kt][r] = sc[kt][r] * SCL + cb;
    }

    // ---- lane-local max over 32 (tree) ----
    float mx[16];
#pragma unroll
    for (int i = 0; i < 16; ++i)
      mx[i] = fmaxf(pp[i >> 1][(i & 1) * 2], pp[i >> 1][(i & 1) * 2 + 1]);
#pragma unroll
    for (int s = 8; s > 0; s >>= 1)
#pragma unroll
      for (int i = 0; i < s; ++i) mx[i] = fmaxf(mx[i], mx[i + s]);
    float tm = mx[0];

    // ---- lazy row-max ----
    if (!__all(tm <= mrun + THR)) {
      tm = fmaxf(tm, __shfl_xor(tm, 16));
      tm = fmaxf(tm, __shfl_xor(tm, 32));
      float mn = fmaxf(mrun, tm);
      float sfv = exp2_raw(mrun - mn);
      mrun = mn;
      lpart *= sfv;
#pragma unroll
      for (int r = 0; r < 4; ++r) {
        float sq = __shfl(sfv, (lane & 48) | (lg * 4 + r));
#pragma unroll
        for (int db = 0; db < 4; ++db) ov[db][r] *= sq;
      }
    }

    // ---- exp2 + per-lane partial sum ----
#pragma unroll
    for (int kt = 0; kt < 8; ++kt)
#pragma unroll
      for (int r = 0; r < 4; ++r)
        pp[kt][r] = exp2_raw(pp[kt][r] - mrun);
    float s16[16];
#pragma unroll
    for (int i = 0; i < 16; ++i)
      s16[i] = pp[i >> 1][(i & 1) * 2] + pp[i >> 1][(i & 1) * 2 + 1];
#pragma unroll
    for (int s = 8; s > 0; s >>= 1)
#pragma unroll
      for (int i = 0; i < s; ++i) s16[i] += s16[i + s];
    lpart += s16[0];

    // ---- pack P: pk[c] packs pp[2c], pp[2c+1] ----
    union { bf16x8 v; unsigned u[4]; } pk[4];
#pragma unroll
    for (int c = 0; c < 4; ++c) {
      asm("v_cvt_pk_bf16_f32 %0, %1, %2"
          : "=v"(pk[c].u[0]) : "v"(pp[2 * c][0]), "v"(pp[2 * c][1]));
      asm("v_cvt_pk_bf16_f32 %0, %1, %2"
          : "=v"(pk[c].u[1]) : "v"(pp[2 * c][2]), "v"(pp[2 * c][3]));
      asm("v_cvt_pk_bf16_f32 %0, %1, %2"
          : "=v"(pk[c].u[2]) : "v"(pp[2 * c + 1][0]), "v"(pp[2 * c + 1][1]));
      asm("v_cvt_pk_bf16_f32 %0, %1, %2"
          : "=v"(pk[c].u[3]) : "v"(pp[2 * c + 1][2]), "v"(pp[2 * c + 1][3]));
    }

    // ---- PV ----
    __builtin_amdgcn_s_setprio(1);
#pragma unroll
    for (int c = 0; c < 4; ++c)
#pragma unroll
      for (int db = 0; db < 4; ++db)
        ov[db] = __builtin_amdgcn_mfma_f32_16x16x32_bf16(
            pk[c].v, vfr[c][db], ov[db], 0, 0, 0);
    __builtin_amdgcn_s_setprio(0);
  }

  // ---- epilogue ----
  float lsum = lpart;
  lsum += __shfl_xor(lsum, 16);
  lsum += __shfl_xor(lsum, 32);
  float invl = 1.0f / lsum;
#pragma unroll
  for (int r = 0; r < 4; ++r) {
    float iv = __shfl(invl, (lane & 48) | (lg * 4 + r));
    size_t row = (size_t)(bb * S_ + qw + lg * 4 + r);
#pragma unroll
    for (int db = 0; db < 4; ++db)
      ctxb[row * 1024 + h * 64 + db * 16 + lr] = f2bf(ov[db][r] * iv);
  }
}

extern "C" void kernel_launch(void* const* d_in, const int* in_sizes, int n_in,
                              void* d_out, int out_size, void* d_ws, size_t ws_size,
                              hipStream_t stream) {
  const float* hs      = (const float*)d_in[0];
  const float* w_qkv   = (const float*)d_in[1];
  const float* b_qkv   = (const float*)d_in[2];
  const float* w_dense = (const float*)d_in[3];
  const float* b_dense = (const float*)d_in[4];
  const float* rtab    = (const float*)d_in[5];
  float* out = (float*)d_out;

  char* ws = (char*)d_ws;
  unsigned short* qkvb = (unsigned short*)ws;                          // 24 MB
  unsigned short* ctxb = (unsigned short*)(ws + (((size_t)24) << 20)); // 8 MB
  unsigned short* hsb  = (unsigned short*)(ws + (((size_t)32) << 20)); // 8 MB
  unsigned short* wqT  = (unsigned short*)(ws + (((size_t)40) << 20)); // 6 MB
  unsigned short* wdT  = (unsigned short*)(ws + (((size_t)46) << 20)); // 2 MB
  unsigned short* vP   = (unsigned short*)(ws + (((size_t)48) << 20)); // 8 MB
  float* biasTab       = (float*)(ws + (((size_t)56) << 20));          // 256 KB

  hipLaunchKernelGGL(prologue_kernel, dim3(3328), dim3(256), 0, stream,
                     hs, hsb, w_qkv, wqT, w_dense, wdT, rtab, biasTab);
  hipLaunchKernelGGL((gemm_mfma_kernel<true>), dim3(24, 32), dim3(256), 0, stream,
                     hsb, wqT, b_qkv, (void*)qkvb, vP, 4096, 3072, 1024);
  hipLaunchKernelGGL(attn_mfma7_kernel, dim3(512), dim3(512), 0, stream,
                     qkvb, vP, biasTab, ctxb);
  hipLaunchKernelGGL((gemm_mfma64_kernel<false>), dim3(8, 64), dim3(256), 0, stream,
                     ctxb, wdT, b_dense, (void*)out, 4096, 1024, 1024);
}

// Round 17
// 133.205 us; speedup vs baseline: 1.0821x; 1.0821x over previous
//
#include <hip/hip_runtime.h>
#include <hip/hip_bf16.h>
#include <math.h>

#define S_ 2048

typedef __attribute__((ext_vector_type(8))) short bf16x8;
typedef __attribute__((ext_vector_type(4))) float f32x4;
typedef __attribute__((ext_vector_type(8))) unsigned short u16x8;
typedef __attribute__((ext_vector_type(4))) unsigned short u16x4;

__device__ inline unsigned short f2bf(float f) {
  union { float f; unsigned u; } x; x.f = f;
  unsigned r = x.u + 0x7fff + ((x.u >> 16) & 1);
  return (unsigned short)(r >> 16);
}

__device__ __forceinline__ float exp2_raw(float x) {
  float r;
  asm("v_exp_f32 %0, %1" : "=v"(r) : "v"(x));
  return r;
}

__device__ __forceinline__ void gll16(const unsigned short* g, unsigned short* l) {
  __builtin_amdgcn_global_load_lds(
      (const __attribute__((address_space(1))) unsigned int*)g,
      (__attribute__((address_space(3))) unsigned int*)l, 16, 0, 0);
}

// ---------------- fused prologue ----------------
__device__ __forceinline__ void transpose_tile(
    const float* __restrict__ in, unsigned short* __restrict__ out,
    int K, int N, int bx, int by, int tid, unsigned short (*tile)[72]) {
  const int k0 = by * 64, n0 = bx * 64;
  const int rr = tid >> 4, cc = (tid & 15) * 4;
#pragma unroll
  for (int p = 0; p < 4; ++p) {
    int k = rr + p * 16;
    float4 v = *(const float4*)&in[(size_t)(k0 + k) * N + n0 + cc];
    tile[k][cc + 0] = f2bf(v.x);
    tile[k][cc + 1] = f2bf(v.y);
    tile[k][cc + 2] = f2bf(v.z);
    tile[k][cc + 3] = f2bf(v.w);
  }
  __syncthreads();
#pragma unroll
  for (int p = 0; p < 4; ++p) {
    int n = rr + p * 16;
    u16x4 o;
    o[0] = tile[cc + 0][n];
    o[1] = tile[cc + 1][n];
    o[2] = tile[cc + 2][n];
    o[3] = tile[cc + 3][n];
    *(u16x4*)&out[(size_t)(n0 + n) * K + k0 + cc] = o;
  }
}

__global__ __launch_bounds__(256) void prologue_kernel(
    const float* __restrict__ hs, unsigned short* __restrict__ hsb,
    const float* __restrict__ w_qkv, unsigned short* __restrict__ wqT,
    const float* __restrict__ w_dense, unsigned short* __restrict__ wdT,
    const float* __restrict__ table, float* __restrict__ biasTab) {
  __shared__ unsigned short tile[64][72];
  const int blk = blockIdx.x;
  const int tid = threadIdx.x;
  if (blk < 2048) {
    int i = blk * 256 + tid;
    float4 a = ((const float4*)hs)[i * 2];
    float4 b = ((const float4*)hs)[i * 2 + 1];
    u16x8 o;
    o[0] = f2bf(a.x); o[1] = f2bf(a.y); o[2] = f2bf(a.z); o[3] = f2bf(a.w);
    o[4] = f2bf(b.x); o[5] = f2bf(b.y); o[6] = f2bf(b.z); o[7] = f2bf(b.w);
    *(u16x8*)&hsb[(size_t)i * 8] = o;
  } else if (blk < 2816) {
    int t = blk - 2048;
    transpose_tile(w_qkv, wqT, 1024, 3072, t % 48, t / 48, tid, tile);
  } else if (blk < 3072) {
    int t = blk - 2816;
    transpose_tile(w_dense, wdT, 1024, 1024, t % 16, t / 16, tid, tile);
  } else {
    int idx = (blk - 3072) * 256 + tid;
    int h = idx >> 12;
    int r = idx & 4095;
    int rel = r - 2047;
    int bucket = rel > 0 ? 16 : 0;
    int ar = rel < 0 ? -rel : rel;
    if (ar < 8) {
      bucket += ar;
    } else {
      float tmp = logf((float)ar / 8.0f);
      float lf = tmp / 2.7725887222397811f * 8.0f;
      int large = 8 + (int)lf;
      bucket += (large < 15 ? large : 15);
    }
    biasTab[idx] = table[h * 32 + bucket] * 1.44269504088896f;  // log2e domain
  }
}

// ------- bf16 MFMA GEMM, 128x128 tile, BK=32, double-buffered (2-phase) ------
// XCD-swizzled. BF16OUT epilogue: Q/K repack->coalesced; V fused vperm -> vP.
template <bool BF16OUT>
__global__ __launch_bounds__(256) void gemm_mfma_kernel(
    const unsigned short* __restrict__ A, const unsigned short* __restrict__ Bt,
    const float* __restrict__ bias, void* __restrict__ Cout,
    unsigned short* __restrict__ vP, int M, int N, int K) {
  __shared__ __align__(16) unsigned short As[2 * 128 * 32];
  __shared__ __align__(16) unsigned short Bs[2 * 128 * 32];
  const int tid = threadIdx.x;
  const int wave = tid >> 6, lane = tid & 63;
  const int lg = lane >> 4, lr = lane & 15;
  const int nbx = gridDim.x;
  const int flat = blockIdx.y * nbx + blockIdx.x;
  const int cpx = (nbx * gridDim.y) >> 3;
  const int swzid = (flat & 7) * cpx + (flat >> 3);
  const int m0 = (swzid / nbx) * 128, n0 = (swzid % nbx) * 128;
  const int wm = (wave & 1) * 64, wn = (wave >> 1) * 64;

  f32x4 acc[4][4] = {};

  // staging (round-13 BK=32 mapping): chunk c = j*256+tid; row r=c>>2,
  // phys slot c&3, src slot (c&3)^(r&3)
  const int r0 = tid >> 2;
  const int sw = ((tid & 3) ^ (r0 & 3)) << 3;
  const unsigned short* aP0 = A + (size_t)(m0 + r0) * K + sw;
  const unsigned short* aP1 = A + (size_t)(m0 + 64 + r0) * K + sw;
  const unsigned short* bP0 = Bt + (size_t)(n0 + r0) * K + sw;
  const unsigned short* bP1 = Bt + (size_t)(n0 + 64 + r0) * K + sw;
  unsigned short* ldsA0 = &As[(tid & ~63) * 8];
  unsigned short* ldsA1 = &As[(256 + (tid & ~63)) * 8];
  unsigned short* ldsB0 = &Bs[(tid & ~63) * 8];
  unsigned short* ldsB1 = &Bs[(256 + (tid & ~63)) * 8];

  const int swz = (lg ^ (lr & 3)) << 3;
  const int NT = K >> 5;

  // prologue: stage tile 0 into buffer 0
  gll16(aP0, ldsA0);
  gll16(aP1, ldsA1);
  gll16(bP0, ldsB0);
  gll16(bP1, ldsB1);

  for (int ti = 0; ti < NT; ++ti) {
    const int cur = ti & 1;
    __syncthreads();   // buf[cur] loads complete; buf[cur^1] reads done
    if (ti + 1 < NT) {
      const int kt = (ti + 1) << 5;
      const int nb = (cur ^ 1) * 4096;
      gll16(aP0 + kt, ldsA0 + nb);
      gll16(aP1 + kt, ldsA1 + nb);
      gll16(bP0 + kt, ldsB0 + nb);
      gll16(bP1 + kt, ldsB1 + nb);
    }
    const unsigned short* Ab = &As[cur * 4096];
    const unsigned short* Bb = &Bs[cur * 4096];
    bf16x8 af[4], bfr[4];
#pragma unroll
    for (int t = 0; t < 4; ++t) {
      af[t]  = *(const bf16x8*)&Ab[(wm + t * 16 + lr) * 32 + swz];
      bfr[t] = *(const bf16x8*)&Bb[(wn + t * 16 + lr) * 32 + swz];
    }
#pragma unroll
    for (int i = 0; i < 4; ++i)
#pragma unroll
      for (int j = 0; j < 4; ++j)
        acc[i][j] = __builtin_amdgcn_mfma_f32_16x16x32_bf16(
            af[i], bfr[j], acc[i][j], 0, 0, 0);
  }

  float bv[4];
#pragma unroll
  for (int j = 0; j < 4; ++j) bv[j] = bias[n0 + wn + j * 16 + lr];

  if constexpr (BF16OUT) {
    __syncthreads();   // all waves' frag reads complete before LDS reuse
    if (n0 < 2048) {
      unsigned short* rp = &As[wave * 1024];
#pragma unroll
      for (int i = 0; i < 4; ++i) {
#pragma unroll
        for (int j = 0; j < 4; ++j) {
          const int cw = ((j + lg) & 3) * 16 + lr;
#pragma unroll
          for (int r = 0; r < 4; ++r)
            rp[(lg * 4 + r) * 64 + cw] = f2bf(acc[i][j][r] + bv[j]);
        }
#pragma unroll
        for (int pass = 0; pass < 2; ++pass) {
          const int row = pass * 8 + (lane >> 3);
          const int cread = ((((lane & 7) >> 1) + (row >> 2)) & 3) * 16 +
                            (lane & 1) * 8;
          u16x8 v = *(const u16x8*)&rp[row * 64 + cread];
          *(u16x8*)&((unsigned short*)Cout)[
              (size_t)(m0 + wm + i * 16 + row) * N + n0 + wn + (lane & 7) * 8] = v;
        }
      }
    } else {
      // ---- V epilogue: fused vperm (64k x 64d per wave) ----
      unsigned short* R = (wave < 2) ? &As[(wave & 1) * 4096]
                                     : &Bs[(wave & 1) * 4096];
#pragma unroll
      for (int i = 0; i < 4; ++i) {
        const int lsv = (i >> 1) * 4 + lg;
        const int ebase = (i & 1) * 4;
#pragma unroll
        for (int j = 0; j < 4; ++j) {
          const int d = j * 16 + lr;
          const int ps = lsv ^ (d & 7);
          u16x4 o;
#pragma unroll
          for (int r = 0; r < 4; ++r) o[r] = f2bf(acc[i][j][r] + bv[j]);
          *(u16x4*)&R[d * 64 + ps * 8 + ebase] = o;
        }
      }
      const int krow0 = m0 + wm;
      const int bbv = krow0 >> 11;
      const int sbase = krow0 & 2047;
      const int h = ((n0 - 2048) >> 6) + (wave >> 1);
#pragma unroll
      for (int it = 0; it < 8; ++it) {
        const int d = it * 8 + (lane >> 3);
        const int c = lane & 7;
        u16x8 v = *(const u16x8*)&R[d * 64 + c * 8];
        *(u16x8*)&vP[((size_t)((bbv * 16 + h) * 64 + d)) * 2048 +
                     sbase + c * 8] = v;
      }
    }
  } else {
#pragma unroll
    for (int i = 0; i < 4; ++i)
#pragma unroll
      for (int j = 0; j < 4; ++j)
#pragma unroll
        for (int r = 0; r < 4; ++r) {
          int row = m0 + wm + i * 16 + lg * 4 + r;
          int col = n0 + wn + j * 16 + lr;
          ((float*)Cout)[(size_t)row * N + col] = acc[i][j][r] + bv[j];
        }
  }
}

// ------- bf16 MFMA GEMM, 64x128 tile, BK=32, double-buffered ----------------
template <bool BF16OUT>
__global__ __launch_bounds__(256) void gemm_mfma64_kernel(
    const unsigned short* __restrict__ A, const unsigned short* __restrict__ Bt,
    const float* __restrict__ bias, void* __restrict__ Cout,
    int M, int N, int K) {
  __shared__ __align__(16) unsigned short As[2 * 64 * 32];
  __shared__ __align__(16) unsigned short Bs[2 * 128 * 32];
  const int tid = threadIdx.x;
  const int wave = tid >> 6, lane = tid & 63;
  const int lg = lane >> 4, lr = lane & 15;
  const int nbx = gridDim.x;
  const int flat = blockIdx.y * nbx + blockIdx.x;
  const int cpx = (nbx * gridDim.y) >> 3;
  const int swzid = (flat & 7) * cpx + (flat >> 3);
  const int m0 = (swzid / nbx) * 64, n0 = (swzid % nbx) * 128;
  const int wm = (wave & 1) * 32, wn = (wave >> 1) * 64;

  f32x4 acc[2][4] = {};

  const int r0 = tid >> 2;
  const int sw = ((tid & 3) ^ (r0 & 3)) << 3;
  const unsigned short* aP  = A + (size_t)(m0 + r0) * K + sw;
  const unsigned short* bP0 = Bt + (size_t)(n0 + r0) * K + sw;
  const unsigned short* bP1 = Bt + (size_t)(n0 + 64 + r0) * K + sw;
  unsigned short* ldsA  = &As[(tid & ~63) * 8];
  unsigned short* ldsB0 = &Bs[(tid & ~63) * 8];
  unsigned short* ldsB1 = &Bs[(256 + (tid & ~63)) * 8];

  const int swz = (lg ^ (lr & 3)) << 3;
  const int NT = K >> 5;

  gll16(aP, ldsA);
  gll16(bP0, ldsB0);
  gll16(bP1, ldsB1);

  for (int ti = 0; ti < NT; ++ti) {
    const int cur = ti & 1;
    __syncthreads();
    if (ti + 1 < NT) {
      const int kt = (ti + 1) << 5;
      gll16(aP + kt, ldsA + (cur ^ 1) * 2048);
      gll16(bP0 + kt, ldsB0 + (cur ^ 1) * 4096);
      gll16(bP1 + kt, ldsB1 + (cur ^ 1) * 4096);
    }
    const unsigned short* Ab = &As[cur * 2048];
    const unsigned short* Bb = &Bs[cur * 4096];
    bf16x8 af[2], bfr[4];
#pragma unroll
    for (int t = 0; t < 2; ++t)
      af[t] = *(const bf16x8*)&Ab[(wm + t * 16 + lr) * 32 + swz];
#pragma unroll
    for (int t = 0; t < 4; ++t)
      bfr[t] = *(const bf16x8*)&Bb[(wn + t * 16 + lr) * 32 + swz];
#pragma unroll
    for (int i = 0; i < 2; ++i)
#pragma unroll
      for (int j = 0; j < 4; ++j)
        acc[i][j] = __builtin_amdgcn_mfma_f32_16x16x32_bf16(
            af[i], bfr[j], acc[i][j], 0, 0, 0);
  }

  float bv[4];
#pragma unroll
  for (int j = 0; j < 4; ++j) bv[j] = bias[n0 + wn + j * 16 + lr];
#pragma unroll
  for (int i = 0; i < 2; ++i) {
#pragma unroll
    for (int j = 0; j < 4; ++j) {
#pragma unroll
      for (int r = 0; r < 4; ++r) {
        int row = m0 + wm + i * 16 + lg * 4 + r;
        int col = n0 + wn + j * 16 + lr;
        float val = acc[i][j][r] + bv[j];
        if constexpr (BF16OUT)
          ((unsigned short*)Cout)[(size_t)row * N + col] = f2bf(val);
        else
          ((float*)Cout)[(size_t)row * N + col] = val;
      }
    }
  }
}

// ---------------- bf16 MFMA flash attention v6 (reverted, proven 58.8us) ------
__global__ __launch_bounds__(512) void attn_mfma6_kernel(
    const unsigned short* __restrict__ qkvb, const unsigned short* __restrict__ vP,
    const float* __restrict__ biasTab, unsigned short* __restrict__ ctxb) {
  const int wg0 = blockIdx.x;
  const int wg = (wg0 & 7) * 64 + (wg0 >> 3);
  const int qt = wg & 15;
  const int h  = (wg >> 4) & 15;
  const int bb = wg >> 8;

  const int tid = threadIdx.x;
  const int wave = tid >> 6;
  const int lane = tid & 63;
  const int lg = lane >> 4;
  const int lr = lane & 15;

  __shared__ __align__(16) unsigned short Klds[2][4096];
  __shared__ __align__(16) unsigned short Vlds[2][4096];
  __shared__ float biasW[2][192];

  const int q0 = qt * 128;
  const int qw = q0 + wave * 16;
  const float SCL = 0.125f * 1.44269504088896f;
  const float THR = 11.5415603f;

  bf16x8 qf[2];
#pragma unroll
  for (int kh = 0; kh < 2; ++kh)
    qf[kh] = *(const bf16x8*)(qkvb +
        (size_t)(bb * S_ + qw + lr) * 3072 + h * 64 + kh * 32 + lg * 8);

  float mrun = -1e30f;
  float lpart = 0.f;
  f32x4 ov[4] = {};

  const int kk = tid >> 3, kpb = tid & 7;
  const unsigned short* kptr = qkvb + (size_t)(bb * S_ + kk) * 3072 + 1024 +
                               h * 64 + (kpb ^ (kk & 7)) * 8;
  const unsigned short* vptr = vP + ((size_t)((bb * 16 + h) * 64 + (tid >> 3))) * S_ +
                               (tid & 7) * 8;
  const float* btabH = biasTab + h * 4096 + 2047;

  auto nonuni = [&](int tt) {
    int rl = tt * 64 - q0;
    return !((rl - 127 >= 91) || (rl + 63 <= -91));
  };

  gll16(kptr, &Klds[0][(tid & ~63) * 8]);
  gll16(vptr, &Vlds[0][(tid & ~63) * 8]);
  if (nonuni(0) && tid < 192) biasW[0][tid] = btabH[-q0 - 127 + tid];

  for (int t = 0; t < 32; ++t) {
    const int cur = t & 1;
    __syncthreads();

    if (t < 31) {
      const size_t kadv = (size_t)(t + 1) * 64 * 3072;
      gll16(kptr + kadv, &Klds[cur ^ 1][(tid & ~63) * 8]);
      gll16(vptr + (t + 1) * 64, &Vlds[cur ^ 1][(tid & ~63) * 8]);
      if (nonuni(t + 1) && tid < 192)
        biasW[cur ^ 1][tid] = btabH[(t + 1) * 64 - q0 - 127 + tid];
    }

    // ---- QK^T swapped ----
    f32x4 sc[4] = {};
    __builtin_amdgcn_s_setprio(1);
#pragma unroll
    for (int kt = 0; kt < 4; ++kt) {
      const unsigned short* kr = &Klds[cur][(kt * 16 + lr) * 64];
      bf16x8 kf0 = *(const bf16x8*)(kr + ((lg)     ^ (lr & 7)) * 8);
      bf16x8 kf1 = *(const bf16x8*)(kr + ((4 + lg) ^ (lr & 7)) * 8);
      sc[kt] = __builtin_amdgcn_mfma_f32_16x16x32_bf16(kf0, qf[0], sc[kt], 0, 0, 0);
      sc[kt] = __builtin_amdgcn_mfma_f32_16x16x32_bf16(kf1, qf[1], sc[kt], 0, 0, 0);
    }
    __builtin_amdgcn_s_setprio(0);

    // ---- V fragments hoisted ----
    bf16x8 vfr[2][4];
#pragma unroll
    for (int kh = 0; kh < 2; ++kh)
#pragma unroll
      for (int db = 0; db < 4; ++db)
        vfr[kh][db] = *(const bf16x8*)&Vlds[cur][
            (db * 16 + lr) * 64 + ((4 * kh + lg) ^ (lr & 7)) * 8];

    // ---- bias (log2e domain) ----
    float pp[4][4];
    if (nonuni(t)) {
      const int bidx = 127 + lg * 4 - wave * 16 - lr;
#pragma unroll
      for (int kt = 0; kt < 4; ++kt)
#pragma unroll
        for (int r = 0; r < 4; ++r)
          pp[kt][r] = sc[kt][r] * SCL + biasW[cur][bidx + kt * 16 + r];
    } else {
      const float cb = btabH[t * 64 - q0];
#pragma unroll
      for (int kt = 0; kt < 4; ++kt)
#pragma unroll
        for (int r = 0; r < 4; ++r)
          pp[kt][r] = sc[kt][r] * SCL + cb;
    }

    // ---- lane-local max (tree) ----
    float mx[8];
#pragma unroll
    for (int i = 0; i < 8; ++i)
      mx[i] = fmaxf(pp[i >> 1][(i & 1) * 2], pp[i >> 1][(i & 1) * 2 + 1]);
    float m01 = fmaxf(mx[0], mx[1]), m23 = fmaxf(mx[2], mx[3]);
    float m45 = fmaxf(mx[4], mx[5]), m67 = fmaxf(mx[6], mx[7]);
    float tm = fmaxf(fmaxf(m01, m23), fmaxf(m45, m67));

    // ---- lazy row-max ----
    if (!__all(tm <= mrun + THR)) {
      tm = fmaxf(tm, __shfl_xor(tm, 16));
      tm = fmaxf(tm, __shfl_xor(tm, 32));
      float mn = fmaxf(mrun, tm);
      float sfv = exp2_raw(mrun - mn);
      mrun = mn;
      lpart *= sfv;
#pragma unroll
      for (int r = 0; r < 4; ++r) {
        float sq = __shfl(sfv, (lane & 48) | (lg * 4 + r));
#pragma unroll
        for (int db = 0; db < 4; ++db) ov[db][r] *= sq;
      }
    }

    // ---- exp2 + per-lane partial sum ----
#pragma unroll
    for (int kt = 0; kt < 4; ++kt)
#pragma unroll
      for (int r = 0; r < 4; ++r)
        pp[kt][r] = exp2_raw(pp[kt][r] - mrun);
    float s8[8];
#pragma unroll
    for (int i = 0; i < 8; ++i)
      s8[i] = pp[i >> 1][(i & 1) * 2] + pp[i >> 1][(i & 1) * 2 + 1];
    float s01 = s8[0] + s8[1], s23 = s8[2] + s8[3];
    float s45 = s8[4] + s8[5], s67 = s8[6] + s8[7];
    lpart += (s01 + s23) + (s45 + s67);

    // ---- pack P via v_cvt_pk_bf16_f32 ----
    union { bf16x8 v; unsigned u[4]; } pk[2];
#pragma unroll
    for (int kh = 0; kh < 2; ++kh) {
      asm("v_cvt_pk_bf16_f32 %0, %1, %2"
          : "=v"(pk[kh].u[0]) : "v"(pp[2 * kh][0]), "v"(pp[2 * kh][1]));
      asm("v_cvt_pk_bf16_f32 %0, %1, %2"
          : "=v"(pk[kh].u[1]) : "v"(pp[2 * kh][2]), "v"(pp[2 * kh][3]));
      asm("v_cvt_pk_bf16_f32 %0, %1, %2"
          : "=v"(pk[kh].u[2]) : "v"(pp[2 * kh + 1][0]), "v"(pp[2 * kh + 1][1]));
      asm("v_cvt_pk_bf16_f32 %0, %1, %2"
          : "=v"(pk[kh].u[3]) : "v"(pp[2 * kh + 1][2]), "v"(pp[2 * kh + 1][3]));
    }

    // ---- PV ----
    __builtin_amdgcn_s_setprio(1);
#pragma unroll
    for (int kh = 0; kh < 2; ++kh)
#pragma unroll
      for (int db = 0; db < 4; ++db)
        ov[db] = __builtin_amdgcn_mfma_f32_16x16x32_bf16(
            pk[kh].v, vfr[kh][db], ov[db], 0, 0, 0);
    __builtin_amdgcn_s_setprio(0);
  }

  // ---- epilogue ----
  float lsum = lpart;
  lsum += __shfl_xor(lsum, 16);
  lsum += __shfl_xor(lsum, 32);
  float invl = 1.0f / lsum;
#pragma unroll
  for (int r = 0; r < 4; ++r) {
    float iv = __shfl(invl, (lane & 48) | (lg * 4 + r));
    size_t row = (size_t)(bb * S_ + qw + lg * 4 + r);
#pragma unroll
    for (int db = 0; db < 4; ++db)
      ctxb[row * 1024 + h * 64 + db * 16 + lr] = f2bf(ov[db][r] * iv);
  }
}

extern "C" void kernel_launch(void* const* d_in, const int* in_sizes, int n_in,
                              void* d_out, int out_size, void* d_ws, size_t ws_size,
                              hipStream_t stream) {
  const float* hs      = (const float*)d_in[0];
  const float* w_qkv   = (const float*)d_in[1];
  const float* b_qkv   = (const float*)d_in[2];
  const float* w_dense = (const float*)d_in[3];
  const float* b_dense = (const float*)d_in[4];
  const float* rtab    = (const float*)d_in[5];
  float* out = (float*)d_out;

  char* ws = (char*)d_ws;
  unsigned short* qkvb = (unsigned short*)ws;                          // 24 MB
  unsigned short* ctxb = (unsigned short*)(ws + (((size_t)24) << 20)); // 8 MB
  unsigned short* hsb  = (unsigned short*)(ws + (((size_t)32) << 20)); // 8 MB
  unsigned short* wqT  = (unsigned short*)(ws + (((size_t)40) << 20)); // 6 MB
  unsigned short* wdT  = (unsigned short*)(ws + (((size_t)46) << 20)); // 2 MB
  unsigned short* vP   = (unsigned short*)(ws + (((size_t)48) << 20)); // 8 MB
  float* biasTab       = (float*)(ws + (((size_t)56) << 20));          // 256 KB

  hipLaunchKernelGGL(prologue_kernel, dim3(3328), dim3(256), 0, stream,
                     hs, hsb, w_qkv, wqT, w_dense, wdT, rtab, biasTab);
  hipLaunchKernelGGL((gemm_mfma_kernel<true>), dim3(24, 32), dim3(256), 0, stream,
                     hsb, wqT, b_qkv, (void*)qkvb, vP, 4096, 3072, 1024);
  hipLaunchKernelGGL(attn_mfma6_kernel, dim3(512), dim3(512), 0, stream,
                     qkvb, vP, biasTab, ctxb);
  hipLaunchKernelGGL((gemm_mfma64_kernel<false>), dim3(8, 64), dim3(256), 0, stream,
                     ctxb, wdT, b_dense, (void*)out, 4096, 1024, 1024);
}

// Round 18
// 132.739 us; speedup vs baseline: 1.0859x; 1.0035x over previous
//
#include <hip/hip_runtime.h>
#include <hip/hip_bf16.h>
#include <math.h>

#define S_ 2048

typedef __attribute__((ext_vector_type(8))) short bf16x8;
typedef __attribute__((ext_vector_type(4))) float f32x4;
typedef __attribute__((ext_vector_type(8))) unsigned short u16x8;
typedef __attribute__((ext_vector_type(4))) unsigned short u16x4;

__device__ inline unsigned short f2bf(float f) {
  union { float f; unsigned u; } x; x.f = f;
  unsigned r = x.u + 0x7fff + ((x.u >> 16) & 1);
  return (unsigned short)(r >> 16);
}

__device__ __forceinline__ float exp2_raw(float x) {
  float r;
  asm("v_exp_f32 %0, %1" : "=v"(r) : "v"(x));
  return r;
}

__device__ __forceinline__ void gll16(const unsigned short* g, unsigned short* l) {
  __builtin_amdgcn_global_load_lds(
      (const __attribute__((address_space(1))) unsigned int*)g,
      (__attribute__((address_space(3))) unsigned int*)l, 16, 0, 0);
}

// ---------------- fused prologue ----------------
__device__ __forceinline__ void transpose_tile(
    const float* __restrict__ in, unsigned short* __restrict__ out,
    int K, int N, int bx, int by, int tid, unsigned short (*tile)[72]) {
  const int k0 = by * 64, n0 = bx * 64;
  const int rr = tid >> 4, cc = (tid & 15) * 4;
#pragma unroll
  for (int p = 0; p < 4; ++p) {
    int k = rr + p * 16;
    float4 v = *(const float4*)&in[(size_t)(k0 + k) * N + n0 + cc];
    tile[k][cc + 0] = f2bf(v.x);
    tile[k][cc + 1] = f2bf(v.y);
    tile[k][cc + 2] = f2bf(v.z);
    tile[k][cc + 3] = f2bf(v.w);
  }
  __syncthreads();
#pragma unroll
  for (int p = 0; p < 4; ++p) {
    int n = rr + p * 16;
    u16x4 o;
    o[0] = tile[cc + 0][n];
    o[1] = tile[cc + 1][n];
    o[2] = tile[cc + 2][n];
    o[3] = tile[cc + 3][n];
    *(u16x4*)&out[(size_t)(n0 + n) * K + k0 + cc] = o;
  }
}

__global__ __launch_bounds__(256) void prologue_kernel(
    const float* __restrict__ hs, unsigned short* __restrict__ hsb,
    const float* __restrict__ w_qkv, unsigned short* __restrict__ wqT,
    const float* __restrict__ w_dense, unsigned short* __restrict__ wdT,
    const float* __restrict__ table, float* __restrict__ biasTab) {
  __shared__ unsigned short tile[64][72];
  const int blk = blockIdx.x;
  const int tid = threadIdx.x;
  if (blk < 2048) {
    int i = blk * 256 + tid;
    float4 a = ((const float4*)hs)[i * 2];
    float4 b = ((const float4*)hs)[i * 2 + 1];
    u16x8 o;
    o[0] = f2bf(a.x); o[1] = f2bf(a.y); o[2] = f2bf(a.z); o[3] = f2bf(a.w);
    o[4] = f2bf(b.x); o[5] = f2bf(b.y); o[6] = f2bf(b.z); o[7] = f2bf(b.w);
    *(u16x8*)&hsb[(size_t)i * 8] = o;
  } else if (blk < 2816) {
    int t = blk - 2048;
    transpose_tile(w_qkv, wqT, 1024, 3072, t % 48, t / 48, tid, tile);
  } else if (blk < 3072) {
    int t = blk - 2816;
    transpose_tile(w_dense, wdT, 1024, 1024, t % 16, t / 16, tid, tile);
  } else {
    int idx = (blk - 3072) * 256 + tid;
    int h = idx >> 12;
    int r = idx & 4095;
    int rel = r - 2047;
    int bucket = rel > 0 ? 16 : 0;
    int ar = rel < 0 ? -rel : rel;
    if (ar < 8) {
      bucket += ar;
    } else {
      float tmp = logf((float)ar / 8.0f);
      float lf = tmp / 2.7725887222397811f * 8.0f;
      int large = 8 + (int)lf;
      bucket += (large < 15 ? large : 15);
    }
    biasTab[idx] = table[h * 32 + bucket] * 1.44269504088896f;  // log2e domain
  }
}

// ------- bf16 MFMA GEMM, 128x128 tile, BK=32, 3-buffer counted-vmcnt ---------
// 2-deep prefetch; s_waitcnt vmcnt(4) in-loop (never 0). XCD-swizzled.
// BF16OUT epilogue: Q/K repack->coalesced; V fused vperm -> vP.
template <bool BF16OUT>
__global__ __launch_bounds__(256) void gemm_mfma_kernel(
    const unsigned short* __restrict__ A, const unsigned short* __restrict__ Bt,
    const float* __restrict__ bias, void* __restrict__ Cout,
    unsigned short* __restrict__ vP, int M, int N, int K) {
  __shared__ __align__(16) unsigned short As[3 * 128 * 32];
  __shared__ __align__(16) unsigned short Bs[3 * 128 * 32];
  const int tid = threadIdx.x;
  const int wave = tid >> 6, lane = tid & 63;
  const int lg = lane >> 4, lr = lane & 15;
  const int nbx = gridDim.x;
  const int flat = blockIdx.y * nbx + blockIdx.x;
  const int cpx = (nbx * gridDim.y) >> 3;
  const int swzid = (flat & 7) * cpx + (flat >> 3);
  const int m0 = (swzid / nbx) * 128, n0 = (swzid % nbx) * 128;
  const int wm = (wave & 1) * 64, wn = (wave >> 1) * 64;

  f32x4 acc[4][4] = {};

  // bias first; materialize so vmcnt counts ONLY staging loads afterward
  float bv[4];
#pragma unroll
  for (int j = 0; j < 4; ++j) bv[j] = bias[n0 + wn + j * 16 + lr];
  asm volatile("" : "+v"(bv[0]), "+v"(bv[1]), "+v"(bv[2]), "+v"(bv[3]));

  // staging (BK=32 mapping): chunk c=j*256+tid; row r=c>>2, slot (c&3)^(r&3)
  const int r0 = tid >> 2;
  const int sw = ((tid & 3) ^ (r0 & 3)) << 3;
  const unsigned short* aP0 = A + (size_t)(m0 + r0) * K + sw;
  const unsigned short* aP1 = A + (size_t)(m0 + 64 + r0) * K + sw;
  const unsigned short* bP0 = Bt + (size_t)(n0 + r0) * K + sw;
  const unsigned short* bP1 = Bt + (size_t)(n0 + 64 + r0) * K + sw;
  const int dstoff = (tid & ~63) * 8;

  const int swz = (lg ^ (lr & 3)) << 3;
  const int NT = K >> 5;   // 32

  auto STAGE = [&](int b, int kt) {
    unsigned short* Ab = &As[b * 4096];
    unsigned short* Bb = &Bs[b * 4096];
    gll16(aP0 + kt, Ab + dstoff);
    gll16(aP1 + kt, Ab + 2048 + dstoff);
    gll16(bP0 + kt, Bb + dstoff);
    gll16(bP1 + kt, Bb + 2048 + dstoff);
  };
  auto COMPUTE = [&](int b) {
    const unsigned short* Ab = &As[b * 4096];
    const unsigned short* Bb = &Bs[b * 4096];
    bf16x8 af[4], bfr[4];
#pragma unroll
    for (int t = 0; t < 4; ++t) {
      af[t]  = *(const bf16x8*)&Ab[(wm + t * 16 + lr) * 32 + swz];
      bfr[t] = *(const bf16x8*)&Bb[(wn + t * 16 + lr) * 32 + swz];
    }
#pragma unroll
    for (int i = 0; i < 4; ++i)
#pragma unroll
      for (int j = 0; j < 4; ++j)
        acc[i][j] = __builtin_amdgcn_mfma_f32_16x16x32_bf16(
            af[i], bfr[j], acc[i][j], 0, 0, 0);
  };

  // prologue: 2-deep prefetch
  STAGE(0, 0);
  STAGE(1, 32);

  int bcur = 0;
  for (int ti = 0; ti < NT - 1; ++ti) {
    asm volatile("s_waitcnt vmcnt(4)" ::: "memory");   // cur done, next in flight
    __builtin_amdgcn_s_barrier();
    if (ti + 2 < NT) {
      const int bs = bcur >= 1 ? bcur - 1 : 2;   // (bcur+2)%3
      STAGE(bs, (ti + 2) << 5);
    }
    COMPUTE(bcur);
    bcur = bcur + 1 < 3 ? bcur + 1 : 0;
  }
  asm volatile("s_waitcnt vmcnt(0)" ::: "memory");
  __builtin_amdgcn_s_barrier();
  COMPUTE(bcur);

  if constexpr (BF16OUT) {
    __syncthreads();   // all waves' frag reads complete before LDS reuse
    if (n0 < 2048) {
      unsigned short* rp = &As[wave * 1024];
#pragma unroll
      for (int i = 0; i < 4; ++i) {
#pragma unroll
        for (int j = 0; j < 4; ++j) {
          const int cw = ((j + lg) & 3) * 16 + lr;
#pragma unroll
          for (int r = 0; r < 4; ++r)
            rp[(lg * 4 + r) * 64 + cw] = f2bf(acc[i][j][r] + bv[j]);
        }
#pragma unroll
        for (int pass = 0; pass < 2; ++pass) {
          const int row = pass * 8 + (lane >> 3);
          const int cread = ((((lane & 7) >> 1) + (row >> 2)) & 3) * 16 +
                            (lane & 1) * 8;
          u16x8 v = *(const u16x8*)&rp[row * 64 + cread];
          *(u16x8*)&((unsigned short*)Cout)[
              (size_t)(m0 + wm + i * 16 + row) * N + n0 + wn + (lane & 7) * 8] = v;
        }
      }
    } else {
      // ---- V epilogue: fused vperm (64k x 64d per wave) ----
      unsigned short* R = (wave < 2) ? &As[(wave & 1) * 4096]
                                     : &Bs[(wave & 1) * 4096];
#pragma unroll
      for (int i = 0; i < 4; ++i) {
        const int lsv = (i >> 1) * 4 + lg;
        const int ebase = (i & 1) * 4;
#pragma unroll
        for (int j = 0; j < 4; ++j) {
          const int d = j * 16 + lr;
          const int ps = lsv ^ (d & 7);
          u16x4 o;
#pragma unroll
          for (int r = 0; r < 4; ++r) o[r] = f2bf(acc[i][j][r] + bv[j]);
          *(u16x4*)&R[d * 64 + ps * 8 + ebase] = o;
        }
      }
      const int krow0 = m0 + wm;
      const int bbv = krow0 >> 11;
      const int sbase = krow0 & 2047;
      const int h = ((n0 - 2048) >> 6) + (wave >> 1);
#pragma unroll
      for (int it = 0; it < 8; ++it) {
        const int d = it * 8 + (lane >> 3);
        const int c = lane & 7;
        u16x8 v = *(const u16x8*)&R[d * 64 + c * 8];
        *(u16x8*)&vP[((size_t)((bbv * 16 + h) * 64 + d)) * 2048 +
                     sbase + c * 8] = v;
      }
    }
  } else {
#pragma unroll
    for (int i = 0; i < 4; ++i)
#pragma unroll
      for (int j = 0; j < 4; ++j)
#pragma unroll
        for (int r = 0; r < 4; ++r) {
          int row = m0 + wm + i * 16 + lg * 4 + r;
          int col = n0 + wn + j * 16 + lr;
          ((float*)Cout)[(size_t)row * N + col] = acc[i][j][r] + bv[j];
        }
  }
}

// ------- bf16 MFMA GEMM, 64x128 tile, BK=32, 3-buffer counted-vmcnt ----------
template <bool BF16OUT>
__global__ __launch_bounds__(256) void gemm_mfma64_kernel(
    const unsigned short* __restrict__ A, const unsigned short* __restrict__ Bt,
    const float* __restrict__ bias, void* __restrict__ Cout,
    int M, int N, int K) {
  __shared__ __align__(16) unsigned short As[3 * 64 * 32];
  __shared__ __align__(16) unsigned short Bs[3 * 128 * 32];
  const int tid = threadIdx.x;
  const int wave = tid >> 6, lane = tid & 63;
  const int lg = lane >> 4, lr = lane & 15;
  const int nbx = gridDim.x;
  const int flat = blockIdx.y * nbx + blockIdx.x;
  const int cpx = (nbx * gridDim.y) >> 3;
  const int swzid = (flat & 7) * cpx + (flat >> 3);
  const int m0 = (swzid / nbx) * 64, n0 = (swzid % nbx) * 128;
  const int wm = (wave & 1) * 32, wn = (wave >> 1) * 64;

  f32x4 acc[2][4] = {};

  float bv[4];
#pragma unroll
  for (int j = 0; j < 4; ++j) bv[j] = bias[n0 + wn + j * 16 + lr];
  asm volatile("" : "+v"(bv[0]), "+v"(bv[1]), "+v"(bv[2]), "+v"(bv[3]));

  const int r0 = tid >> 2;
  const int sw = ((tid & 3) ^ (r0 & 3)) << 3;
  const unsigned short* aP  = A + (size_t)(m0 + r0) * K + sw;
  const unsigned short* bP0 = Bt + (size_t)(n0 + r0) * K + sw;
  const unsigned short* bP1 = Bt + (size_t)(n0 + 64 + r0) * K + sw;
  const int dstoff = (tid & ~63) * 8;

  const int swz = (lg ^ (lr & 3)) << 3;
  const int NT = K >> 5;

  auto STAGE = [&](int b, int kt) {
    gll16(aP + kt, &As[b * 2048] + dstoff);
    gll16(bP0 + kt, &Bs[b * 4096] + dstoff);
    gll16(bP1 + kt, &Bs[b * 4096 + 2048] + dstoff);
  };
  auto COMPUTE = [&](int b) {
    const unsigned short* Ab = &As[b * 2048];
    const unsigned short* Bb = &Bs[b * 4096];
    bf16x8 af[2], bfr[4];
#pragma unroll
    for (int t = 0; t < 2; ++t)
      af[t] = *(const bf16x8*)&Ab[(wm + t * 16 + lr) * 32 + swz];
#pragma unroll
    for (int t = 0; t < 4; ++t)
      bfr[t] = *(const bf16x8*)&Bb[(wn + t * 16 + lr) * 32 + swz];
#pragma unroll
    for (int i = 0; i < 2; ++i)
#pragma unroll
      for (int j = 0; j < 4; ++j)
        acc[i][j] = __builtin_amdgcn_mfma_f32_16x16x32_bf16(
            af[i], bfr[j], acc[i][j], 0, 0, 0);
  };

  STAGE(0, 0);
  STAGE(1, 32);

  int bcur = 0;
  for (int ti = 0; ti < NT - 1; ++ti) {
    asm volatile("s_waitcnt vmcnt(3)" ::: "memory");
    __builtin_amdgcn_s_barrier();
    if (ti + 2 < NT) {
      const int bs = bcur >= 1 ? bcur - 1 : 2;
      STAGE(bs, (ti + 2) << 5);
    }
    COMPUTE(bcur);
    bcur = bcur + 1 < 3 ? bcur + 1 : 0;
  }
  asm volatile("s_waitcnt vmcnt(0)" ::: "memory");
  __builtin_amdgcn_s_barrier();
  COMPUTE(bcur);

#pragma unroll
  for (int i = 0; i < 2; ++i) {
#pragma unroll
    for (int j = 0; j < 4; ++j) {
#pragma unroll
      for (int r = 0; r < 4; ++r) {
        int row = m0 + wm + i * 16 + lg * 4 + r;
        int col = n0 + wn + j * 16 + lr;
        float val = acc[i][j][r] + bv[j];
        if constexpr (BF16OUT)
          ((unsigned short*)Cout)[(size_t)row * N + col] = f2bf(val);
        else
          ((float*)Cout)[(size_t)row * N + col] = val;
      }
    }
  }
}

// ---------------- bf16 MFMA flash attention v6 (proven 58.6us) ----------------
__global__ __launch_bounds__(512) void attn_mfma6_kernel(
    const unsigned short* __restrict__ qkvb, const unsigned short* __restrict__ vP,
    const float* __restrict__ biasTab, unsigned short* __restrict__ ctxb) {
  const int wg0 = blockIdx.x;
  const int wg = (wg0 & 7) * 64 + (wg0 >> 3);
  const int qt = wg & 15;
  const int h  = (wg >> 4) & 15;
  const int bb = wg >> 8;

  const int tid = threadIdx.x;
  const int wave = tid >> 6;
  const int lane = tid & 63;
  const int lg = lane >> 4;
  const int lr = lane & 15;

  __shared__ __align__(16) unsigned short Klds[2][4096];
  __shared__ __align__(16) unsigned short Vlds[2][4096];
  __shared__ float biasW[2][192];

  const int q0 = qt * 128;
  const int qw = q0 + wave * 16;
  const float SCL = 0.125f * 1.44269504088896f;
  const float THR = 11.5415603f;

  bf16x8 qf[2];
#pragma unroll
  for (int kh = 0; kh < 2; ++kh)
    qf[kh] = *(const bf16x8*)(qkvb +
        (size_t)(bb * S_ + qw + lr) * 3072 + h * 64 + kh * 32 + lg * 8);

  float mrun = -1e30f;
  float lpart = 0.f;
  f32x4 ov[4] = {};

  const int kk = tid >> 3, kpb = tid & 7;
  const unsigned short* kptr = qkvb + (size_t)(bb * S_ + kk) * 3072 + 1024 +
                               h * 64 + (kpb ^ (kk & 7)) * 8;
  const unsigned short* vptr = vP + ((size_t)((bb * 16 + h) * 64 + (tid >> 3))) * S_ +
                               (tid & 7) * 8;
  const float* btabH = biasTab + h * 4096 + 2047;

  auto nonuni = [&](int tt) {
    int rl = tt * 64 - q0;
    return !((rl - 127 >= 91) || (rl + 63 <= -91));
  };

  gll16(kptr, &Klds[0][(tid & ~63) * 8]);
  gll16(vptr, &Vlds[0][(tid & ~63) * 8]);
  if (nonuni(0) && tid < 192) biasW[0][tid] = btabH[-q0 - 127 + tid];

  for (int t = 0; t < 32; ++t) {
    const int cur = t & 1;
    __syncthreads();

    if (t < 31) {
      const size_t kadv = (size_t)(t + 1) * 64 * 3072;
      gll16(kptr + kadv, &Klds[cur ^ 1][(tid & ~63) * 8]);
      gll16(vptr + (t + 1) * 64, &Vlds[cur ^ 1][(tid & ~63) * 8]);
      if (nonuni(t + 1) && tid < 192)
        biasW[cur ^ 1][tid] = btabH[(t + 1) * 64 - q0 - 127 + tid];
    }

    f32x4 sc[4] = {};
    __builtin_amdgcn_s_setprio(1);
#pragma unroll
    for (int kt = 0; kt < 4; ++kt) {
      const unsigned short* kr = &Klds[cur][(kt * 16 + lr) * 64];
      bf16x8 kf0 = *(const bf16x8*)(kr + ((lg)     ^ (lr & 7)) * 8);
      bf16x8 kf1 = *(const bf16x8*)(kr + ((4 + lg) ^ (lr & 7)) * 8);
      sc[kt] = __builtin_amdgcn_mfma_f32_16x16x32_bf16(kf0, qf[0], sc[kt], 0, 0, 0);
      sc[kt] = __builtin_amdgcn_mfma_f32_16x16x32_bf16(kf1, qf[1], sc[kt], 0, 0, 0);
    }
    __builtin_amdgcn_s_setprio(0);

    bf16x8 vfr[2][4];
#pragma unroll
    for (int kh = 0; kh < 2; ++kh)
#pragma unroll
      for (int db = 0; db < 4; ++db)
        vfr[kh][db] = *(const bf16x8*)&Vlds[cur][
            (db * 16 + lr) * 64 + ((4 * kh + lg) ^ (lr & 7)) * 8];

    float pp[4][4];
    if (nonuni(t)) {
      const int bidx = 127 + lg * 4 - wave * 16 - lr;
#pragma unroll
      for (int kt = 0; kt < 4; ++kt)
#pragma unroll
        for (int r = 0; r < 4; ++r)
          pp[kt][r] = sc[kt][r] * SCL + biasW[cur][bidx + kt * 16 + r];
    } else {
      const float cb = btabH[t * 64 - q0];
#pragma unroll
      for (int kt = 0; kt < 4; ++kt)
#pragma unroll
        for (int r = 0; r < 4; ++r)
          pp[kt][r] = sc[kt][r] * SCL + cb;
    }

    float mx[8];
#pragma unroll
    for (int i = 0; i < 8; ++i)
      mx[i] = fmaxf(pp[i >> 1][(i & 1) * 2], pp[i >> 1][(i & 1) * 2 + 1]);
    float m01 = fmaxf(mx[0], mx[1]), m23 = fmaxf(mx[2], mx[3]);
    float m45 = fmaxf(mx[4], mx[5]), m67 = fmaxf(mx[6], mx[7]);
    float tm = fmaxf(fmaxf(m01, m23), fmaxf(m45, m67));

    if (!__all(tm <= mrun + THR)) {
      tm = fmaxf(tm, __shfl_xor(tm, 16));
      tm = fmaxf(tm, __shfl_xor(tm, 32));
      float mn = fmaxf(mrun, tm);
      float sfv = exp2_raw(mrun - mn);
      mrun = mn;
      lpart *= sfv;
#pragma unroll
      for (int r = 0; r < 4; ++r) {
        float sq = __shfl(sfv, (lane & 48) | (lg * 4 + r));
#pragma unroll
        for (int db = 0; db < 4; ++db) ov[db][r] *= sq;
      }
    }

#pragma unroll
    for (int kt = 0; kt < 4; ++kt)
#pragma unroll
      for (int r = 0; r < 4; ++r)
        pp[kt][r] = exp2_raw(pp[kt][r] - mrun);
    float s8[8];
#pragma unroll
    for (int i = 0; i < 8; ++i)
      s8[i] = pp[i >> 1][(i & 1) * 2] + pp[i >> 1][(i & 1) * 2 + 1];
    float s01 = s8[0] + s8[1], s23 = s8[2] + s8[3];
    float s45 = s8[4] + s8[5], s67 = s8[6] + s8[7];
    lpart += (s01 + s23) + (s45 + s67);

    union { bf16x8 v; unsigned u[4]; } pk[2];
#pragma unroll
    for (int kh = 0; kh < 2; ++kh) {
      asm("v_cvt_pk_bf16_f32 %0, %1, %2"
          : "=v"(pk[kh].u[0]) : "v"(pp[2 * kh][0]), "v"(pp[2 * kh][1]));
      asm("v_cvt_pk_bf16_f32 %0, %1, %2"
          : "=v"(pk[kh].u[1]) : "v"(pp[2 * kh][2]), "v"(pp[2 * kh][3]));
      asm("v_cvt_pk_bf16_f32 %0, %1, %2"
          : "=v"(pk[kh].u[2]) : "v"(pp[2 * kh + 1][0]), "v"(pp[2 * kh + 1][1]));
      asm("v_cvt_pk_bf16_f32 %0, %1, %2"
          : "=v"(pk[kh].u[3]) : "v"(pp[2 * kh + 1][2]), "v"(pp[2 * kh + 1][3]));
    }

    __builtin_amdgcn_s_setprio(1);
#pragma unroll
    for (int kh = 0; kh < 2; ++kh)
#pragma unroll
      for (int db = 0; db < 4; ++db)
        ov[db] = __builtin_amdgcn_mfma_f32_16x16x32_bf16(
            pk[kh].v, vfr[kh][db], ov[db], 0, 0, 0);
    __builtin_amdgcn_s_setprio(0);
  }

  float lsum = lpart;
  lsum += __shfl_xor(lsum, 16);
  lsum += __shfl_xor(lsum, 32);
  float invl = 1.0f / lsum;
#pragma unroll
  for (int r = 0; r < 4; ++r) {
    float iv = __shfl(invl, (lane & 48) | (lg * 4 + r));
    size_t row = (size_t)(bb * S_ + qw + lg * 4 + r);
#pragma unroll
    for (int db = 0; db < 4; ++db)
      ctxb[row * 1024 + h * 64 + db * 16 + lr] = f2bf(ov[db][r] * iv);
  }
}

extern "C" void kernel_launch(void* const* d_in, const int* in_sizes, int n_in,
                              void* d_out, int out_size, void* d_ws, size_t ws_size,
                              hipStream_t stream) {
  const float* hs      = (const float*)d_in[0];
  const float* w_qkv   = (const float*)d_in[1];
  const float* b_qkv   = (const float*)d_in[2];
  const float* w_dense = (const float*)d_in[3];
  const float* b_dense = (const float*)d_in[4];
  const float* rtab    = (const float*)d_in[5];
  float* out = (float*)d_out;

  char* ws = (char*)d_ws;
  unsigned short* qkvb = (unsigned short*)ws;                          // 24 MB
  unsigned short* ctxb = (unsigned short*)(ws + (((size_t)24) << 20)); // 8 MB
  unsigned short* hsb  = (unsigned short*)(ws + (((size_t)32) << 20)); // 8 MB
  unsigned short* wqT  = (unsigned short*)(ws + (((size_t)40) << 20)); // 6 MB
  unsigned short* wdT  = (unsigned short*)(ws + (((size_t)46) << 20)); // 2 MB
  unsigned short* vP   = (unsigned short*)(ws + (((size_t)48) << 20)); // 8 MB
  float* biasTab       = (float*)(ws + (((size_t)56) << 20));          // 256 KB

  hipLaunchKernelGGL(prologue_kernel, dim3(3328), dim3(256), 0, stream,
                     hs, hsb, w_qkv, wqT, w_dense, wdT, rtab, biasTab);
  hipLaunchKernelGGL((gemm_mfma_kernel<true>), dim3(24, 32), dim3(256), 0, stream,
                     hsb, wqT, b_qkv, (void*)qkvb, vP, 4096, 3072, 1024);
  hipLaunchKernelGGL(attn_mfma6_kernel, dim3(512), dim3(512), 0, stream,
                     qkvb, vP, biasTab, ctxb);
  hipLaunchKernelGGL((gemm_mfma64_kernel<false>), dim3(8, 64), dim3(256), 0, stream,
                     ctxb, wdT, b_dense, (void*)out, 4096, 1024, 1024);
}

// Round 19
// 127.474 us; speedup vs baseline: 1.1308x; 1.0413x over previous
//
#include <hip/hip_runtime.h>
#include <hip/hip_bf16.h>
#include <math.h>

#define S_ 2048

typedef __attribute__((ext_vector_type(8))) short bf16x8;
typedef __attribute__((ext_vector_type(4))) float f32x4;
typedef __attribute__((ext_vector_type(8))) unsigned short u16x8;
typedef __attribute__((ext_vector_type(4))) unsigned short u16x4;

__device__ inline unsigned short f2bf(float f) {
  union { float f; unsigned u; } x; x.f = f;
  unsigned r = x.u + 0x7fff + ((x.u >> 16) & 1);
  return (unsigned short)(r >> 16);
}

__device__ __forceinline__ float exp2_raw(float x) {
  float r;
  asm("v_exp_f32 %0, %1" : "=v"(r) : "v"(x));
  return r;
}

__device__ __forceinline__ void gll16(const unsigned short* g, unsigned short* l) {
  __builtin_amdgcn_global_load_lds(
      (const __attribute__((address_space(1))) unsigned int*)g,
      (__attribute__((address_space(3))) unsigned int*)l, 16, 0, 0);
}

// ---------------- fused prologue ----------------
__device__ __forceinline__ void transpose_tile(
    const float* __restrict__ in, unsigned short* __restrict__ out,
    int K, int N, int bx, int by, int tid, unsigned short (*tile)[72]) {
  const int k0 = by * 64, n0 = bx * 64;
  const int rr = tid >> 4, cc = (tid & 15) * 4;
#pragma unroll
  for (int p = 0; p < 4; ++p) {
    int k = rr + p * 16;
    float4 v = *(const float4*)&in[(size_t)(k0 + k) * N + n0 + cc];
    tile[k][cc + 0] = f2bf(v.x);
    tile[k][cc + 1] = f2bf(v.y);
    tile[k][cc + 2] = f2bf(v.z);
    tile[k][cc + 3] = f2bf(v.w);
  }
  __syncthreads();
#pragma unroll
  for (int p = 0; p < 4; ++p) {
    int n = rr + p * 16;
    u16x4 o;
    o[0] = tile[cc + 0][n];
    o[1] = tile[cc + 1][n];
    o[2] = tile[cc + 2][n];
    o[3] = tile[cc + 3][n];
    *(u16x4*)&out[(size_t)(n0 + n) * K + k0 + cc] = o;
  }
}

__global__ __launch_bounds__(256) void prologue_kernel(
    const float* __restrict__ hs, unsigned short* __restrict__ hsb,
    const float* __restrict__ w_qkv, unsigned short* __restrict__ wqT,
    const float* __restrict__ w_dense, unsigned short* __restrict__ wdT,
    const float* __restrict__ table, float* __restrict__ biasTab) {
  __shared__ unsigned short tile[64][72];
  const int blk = blockIdx.x;
  const int tid = threadIdx.x;
  if (blk < 2048) {
    int i = blk * 256 + tid;
    float4 a = ((const float4*)hs)[i * 2];
    float4 b = ((const float4*)hs)[i * 2 + 1];
    u16x8 o;
    o[0] = f2bf(a.x); o[1] = f2bf(a.y); o[2] = f2bf(a.z); o[3] = f2bf(a.w);
    o[4] = f2bf(b.x); o[5] = f2bf(b.y); o[6] = f2bf(b.z); o[7] = f2bf(b.w);
    *(u16x8*)&hsb[(size_t)i * 8] = o;
  } else if (blk < 2816) {
    int t = blk - 2048;
    transpose_tile(w_qkv, wqT, 1024, 3072, t % 48, t / 48, tid, tile);
  } else if (blk < 3072) {
    int t = blk - 2816;
    transpose_tile(w_dense, wdT, 1024, 1024, t % 16, t / 16, tid, tile);
  } else {
    int idx = (blk - 3072) * 256 + tid;
    int h = idx >> 12;
    int r = idx & 4095;
    int rel = r - 2047;
    int bucket = rel > 0 ? 16 : 0;
    int ar = rel < 0 ? -rel : rel;
    if (ar < 8) {
      bucket += ar;
    } else {
      float tmp = logf((float)ar / 8.0f);
      float lf = tmp / 2.7725887222397811f * 8.0f;
      int large = 8 + (int)lf;
      bucket += (large < 15 ? large : 15);
    }
    biasTab[idx] = table[h * 32 + bucket] * 1.44269504088896f;  // log2e domain
  }
}

// ------- bf16 MFMA GEMM, 128x128 tile, BK=64: C = A @ Bt^T + bias ------------
// XCD-swizzled. BF16OUT epilogue: Q/K repack->coalesced; V fused vperm -> vP.
template <bool BF16OUT>
__global__ __launch_bounds__(256) void gemm_mfma_kernel(
    const unsigned short* __restrict__ A, const unsigned short* __restrict__ Bt,
    const float* __restrict__ bias, void* __restrict__ Cout,
    unsigned short* __restrict__ vP, int M, int N, int K) {
  __shared__ __align__(16) unsigned short As[128 * 64];
  __shared__ __align__(16) unsigned short Bs[128 * 64];
  const int tid = threadIdx.x;
  const int wave = tid >> 6, lane = tid & 63;
  const int lg = lane >> 4, lr = lane & 15;
  const int nbx = gridDim.x;
  const int flat = blockIdx.y * nbx + blockIdx.x;
  const int cpx = (nbx * gridDim.y) >> 3;
  const int swzid = (flat & 7) * cpx + (flat >> 3);
  const int m0 = (swzid / nbx) * 128, n0 = (swzid % nbx) * 128;
  const int wm = (wave & 1) * 64, wn = (wave >> 1) * 64;

  f32x4 acc[4][4] = {};

  const int rbase = tid >> 3;
  const int lsw = ((tid & 7) ^ (rbase & 7)) * 8;
  const unsigned short* aP[4];
  const unsigned short* bP[4];
  unsigned short* ldsA[4];
  unsigned short* ldsB[4];
#pragma unroll
  for (int g = 0; g < 4; ++g) {
    aP[g] = A + (size_t)(m0 + g * 32 + rbase) * K + lsw;
    bP[g] = Bt + (size_t)(n0 + g * 32 + rbase) * K + lsw;
    ldsA[g] = &As[g * 2048 + (tid & ~63) * 8];
    ldsB[g] = &Bs[g * 2048 + (tid & ~63) * 8];
  }

  for (int kt = 0; kt < K; kt += 64) {
    __syncthreads();
#pragma unroll
    for (int g = 0; g < 4; ++g) {
      gll16(aP[g] + kt, ldsA[g]);
      gll16(bP[g] + kt, ldsB[g]);
    }
    __syncthreads();
#pragma unroll
    for (int kh = 0; kh < 2; ++kh) {
      bf16x8 af[4], bfr[4];
#pragma unroll
      for (int t = 0; t < 4; ++t) {
        const int slot = ((kh * 4 + lg) ^ (lr & 7)) * 8;
        af[t]  = *(const bf16x8*)&As[(wm + t * 16 + lr) * 64 + slot];
        bfr[t] = *(const bf16x8*)&Bs[(wn + t * 16 + lr) * 64 + slot];
      }
#pragma unroll
      for (int i = 0; i < 4; ++i)
#pragma unroll
        for (int j = 0; j < 4; ++j)
          acc[i][j] = __builtin_amdgcn_mfma_f32_16x16x32_bf16(
              af[i], bfr[j], acc[i][j], 0, 0, 0);
    }
  }

  float bv[4];
#pragma unroll
  for (int j = 0; j < 4; ++j) bv[j] = bias[n0 + wn + j * 16 + lr];

  if constexpr (BF16OUT) {
    __syncthreads();   // all waves' frag reads of As/Bs complete before reuse
    if (n0 < 2048) {
      unsigned short* rp = &As[wave * 1024];
#pragma unroll
      for (int i = 0; i < 4; ++i) {
#pragma unroll
        for (int j = 0; j < 4; ++j) {
          const int cw = ((j + lg) & 3) * 16 + lr;
#pragma unroll
          for (int r = 0; r < 4; ++r)
            rp[(lg * 4 + r) * 64 + cw] = f2bf(acc[i][j][r] + bv[j]);
        }
#pragma unroll
        for (int pass = 0; pass < 2; ++pass) {
          const int row = pass * 8 + (lane >> 3);
          const int cread = ((((lane & 7) >> 1) + (row >> 2)) & 3) * 16 +
                            (lane & 1) * 8;
          u16x8 v = *(const u16x8*)&rp[row * 64 + cread];
          *(u16x8*)&((unsigned short*)Cout)[
              (size_t)(m0 + wm + i * 16 + row) * N + n0 + wn + (lane & 7) * 8] = v;
        }
      }
    } else {
      // ---- V epilogue: fused vperm (64k x 64d per wave) ----
      unsigned short* R = (wave < 2) ? &As[(wave & 1) * 4096]
                                     : &Bs[(wave & 1) * 4096];
#pragma unroll
      for (int i = 0; i < 4; ++i) {
        const int lsv = (i >> 1) * 4 + lg;
        const int ebase = (i & 1) * 4;
#pragma unroll
        for (int j = 0; j < 4; ++j) {
          const int d = j * 16 + lr;
          const int ps = lsv ^ (d & 7);
          u16x4 o;
#pragma unroll
          for (int r = 0; r < 4; ++r) o[r] = f2bf(acc[i][j][r] + bv[j]);
          *(u16x4*)&R[d * 64 + ps * 8 + ebase] = o;
        }
      }
      const int krow0 = m0 + wm;
      const int bbv = krow0 >> 11;
      const int sbase = krow0 & 2047;
      const int h = ((n0 - 2048) >> 6) + (wave >> 1);
#pragma unroll
      for (int it = 0; it < 8; ++it) {
        const int d = it * 8 + (lane >> 3);
        const int c = lane & 7;
        u16x8 v = *(const u16x8*)&R[d * 64 + c * 8];
        *(u16x8*)&vP[((size_t)((bbv * 16 + h) * 64 + d)) * 2048 +
                     sbase + c * 8] = v;
      }
    }
  } else {
#pragma unroll
    for (int i = 0; i < 4; ++i)
#pragma unroll
      for (int j = 0; j < 4; ++j)
#pragma unroll
        for (int r = 0; r < 4; ++r) {
          int row = m0 + wm + i * 16 + lg * 4 + r;
          int col = n0 + wn + j * 16 + lr;
          ((float*)Cout)[(size_t)row * N + col] = acc[i][j][r] + bv[j];
        }
  }
}

// ------- bf16 MFMA GEMM, 64x128 tile, BK=64 (2x occupancy, small shapes) -----
template <bool BF16OUT>
__global__ __launch_bounds__(256) void gemm_mfma64_kernel(
    const unsigned short* __restrict__ A, const unsigned short* __restrict__ Bt,
    const float* __restrict__ bias, void* __restrict__ Cout,
    int M, int N, int K) {
  __shared__ __align__(16) unsigned short As[64 * 64];
  __shared__ __align__(16) unsigned short Bs[128 * 64];
  const int tid = threadIdx.x;
  const int wave = tid >> 6, lane = tid & 63;
  const int lg = lane >> 4, lr = lane & 15;
  const int nbx = gridDim.x;
  const int flat = blockIdx.y * nbx + blockIdx.x;
  const int cpx = (nbx * gridDim.y) >> 3;
  const int swzid = (flat & 7) * cpx + (flat >> 3);
  const int m0 = (swzid / nbx) * 64, n0 = (swzid % nbx) * 128;
  const int wm = (wave & 1) * 32, wn = (wave >> 1) * 64;

  f32x4 acc[2][4] = {};

  const int rbase = tid >> 3;
  const int lsw = ((tid & 7) ^ (rbase & 7)) * 8;
  const unsigned short* aP[2];
  const unsigned short* bP[4];
  unsigned short* ldsA[2];
  unsigned short* ldsB[4];
#pragma unroll
  for (int g = 0; g < 2; ++g) {
    aP[g] = A + (size_t)(m0 + g * 32 + rbase) * K + lsw;
    ldsA[g] = &As[g * 2048 + (tid & ~63) * 8];
  }
#pragma unroll
  for (int g = 0; g < 4; ++g) {
    bP[g] = Bt + (size_t)(n0 + g * 32 + rbase) * K + lsw;
    ldsB[g] = &Bs[g * 2048 + (tid & ~63) * 8];
  }

  for (int kt = 0; kt < K; kt += 64) {
    __syncthreads();
#pragma unroll
    for (int g = 0; g < 2; ++g) gll16(aP[g] + kt, ldsA[g]);
#pragma unroll
    for (int g = 0; g < 4; ++g) gll16(bP[g] + kt, ldsB[g]);
    __syncthreads();
#pragma unroll
    for (int kh = 0; kh < 2; ++kh) {
      bf16x8 af[2], bfr[4];
      const int slotb = ((kh * 4 + lg) ^ (lr & 7)) * 8;
#pragma unroll
      for (int t = 0; t < 2; ++t)
        af[t] = *(const bf16x8*)&As[(wm + t * 16 + lr) * 64 + slotb];
#pragma unroll
      for (int t = 0; t < 4; ++t)
        bfr[t] = *(const bf16x8*)&Bs[(wn + t * 16 + lr) * 64 + slotb];
#pragma unroll
      for (int i = 0; i < 2; ++i)
#pragma unroll
        for (int j = 0; j < 4; ++j)
          acc[i][j] = __builtin_amdgcn_mfma_f32_16x16x32_bf16(
              af[i], bfr[j], acc[i][j], 0, 0, 0);
    }
  }

  float bv[4];
#pragma unroll
  for (int j = 0; j < 4; ++j) bv[j] = bias[n0 + wn + j * 16 + lr];
#pragma unroll
  for (int i = 0; i < 2; ++i) {
#pragma unroll
    for (int j = 0; j < 4; ++j) {
#pragma unroll
      for (int r = 0; r < 4; ++r) {
        int row = m0 + wm + i * 16 + lg * 4 + r;
        int col = n0 + wn + j * 16 + lr;
        float val = acc[i][j][r] + bv[j];
        if constexpr (BF16OUT)
          ((unsigned short*)Cout)[(size_t)row * N + col] = f2bf(val);
        else
          ((float*)Cout)[(size_t)row * N + col] = val;
      }
    }
  }
}

// ---------------- bf16 MFMA flash attention v6 (+ V-frag hoist) ----------------
__global__ __launch_bounds__(512) void attn_mfma6_kernel(
    const unsigned short* __restrict__ qkvb, const unsigned short* __restrict__ vP,
    const float* __restrict__ biasTab, unsigned short* __restrict__ ctxb) {
  const int wg0 = blockIdx.x;
  const int wg = (wg0 & 7) * 64 + (wg0 >> 3);
  const int qt = wg & 15;
  const int h  = (wg >> 4) & 15;
  const int bb = wg >> 8;

  const int tid = threadIdx.x;
  const int wave = tid >> 6;
  const int lane = tid & 63;
  const int lg = lane >> 4;
  const int lr = lane & 15;

  __shared__ __align__(16) unsigned short Klds[2][4096];
  __shared__ __align__(16) unsigned short Vlds[2][4096];
  __shared__ float biasW[2][192];

  const int q0 = qt * 128;
  const int qw = q0 + wave * 16;
  const float SCL = 0.125f * 1.44269504088896f;
  const float THR = 11.5415603f;

  bf16x8 qf[2];
#pragma unroll
  for (int kh = 0; kh < 2; ++kh)
    qf[kh] = *(const bf16x8*)(qkvb +
        (size_t)(bb * S_ + qw + lr) * 3072 + h * 64 + kh * 32 + lg * 8);

  float mrun = -1e30f;
  float lpart = 0.f;
  f32x4 ov[4] = {};

  const int kk = tid >> 3, kpb = tid & 7;
  const unsigned short* kptr = qkvb + (size_t)(bb * S_ + kk) * 3072 + 1024 +
                               h * 64 + (kpb ^ (kk & 7)) * 8;
  const unsigned short* vptr = vP + ((size_t)((bb * 16 + h) * 64 + (tid >> 3))) * S_ +
                               (tid & 7) * 8;
  const float* btabH = biasTab + h * 4096 + 2047;

  auto nonuni = [&](int tt) {
    int rl = tt * 64 - q0;
    return !((rl - 127 >= 91) || (rl + 63 <= -91));
  };

  gll16(kptr, &Klds[0][(tid & ~63) * 8]);
  gll16(vptr, &Vlds[0][(tid & ~63) * 8]);
  if (nonuni(0) && tid < 192) biasW[0][tid] = btabH[-q0 - 127 + tid];

  for (int t = 0; t < 32; ++t) {
    const int cur = t & 1;
    __syncthreads();

    if (t < 31) {
      const size_t kadv = (size_t)(t + 1) * 64 * 3072;
      gll16(kptr + kadv, &Klds[cur ^ 1][(tid & ~63) * 8]);
      gll16(vptr + (t + 1) * 64, &Vlds[cur ^ 1][(tid & ~63) * 8]);
      if (nonuni(t + 1) && tid < 192)
        biasW[cur ^ 1][tid] = btabH[(t + 1) * 64 - q0 - 127 + tid];
    }

    // ---- QK^T swapped ----
    f32x4 sc[4] = {};
    __builtin_amdgcn_s_setprio(1);
#pragma unroll
    for (int kt = 0; kt < 4; ++kt) {
      const unsigned short* kr = &Klds[cur][(kt * 16 + lr) * 64];
      bf16x8 kf0 = *(const bf16x8*)(kr + ((lg)     ^ (lr & 7)) * 8);
      bf16x8 kf1 = *(const bf16x8*)(kr + ((4 + lg) ^ (lr & 7)) * 8);
      sc[kt] = __builtin_amdgcn_mfma_f32_16x16x32_bf16(kf0, qf[0], sc[kt], 0, 0, 0);
      sc[kt] = __builtin_amdgcn_mfma_f32_16x16x32_bf16(kf1, qf[1], sc[kt], 0, 0, 0);
    }
    __builtin_amdgcn_s_setprio(0);

    // ---- V fragments hoisted ----
    bf16x8 vfr[2][4];
#pragma unroll
    for (int kh = 0; kh < 2; ++kh)
#pragma unroll
      for (int db = 0; db < 4; ++db)
        vfr[kh][db] = *(const bf16x8*)&Vlds[cur][
            (db * 16 + lr) * 64 + ((4 * kh + lg) ^ (lr & 7)) * 8];

    // ---- bias (log2e domain) ----
    float pp[4][4];
    if (nonuni(t)) {
      const int bidx = 127 + lg * 4 - wave * 16 - lr;
#pragma unroll
      for (int kt = 0; kt < 4; ++kt)
#pragma unroll
        for (int r = 0; r < 4; ++r)
          pp[kt][r] = sc[kt][r] * SCL + biasW[cur][bidx + kt * 16 + r];
    } else {
      const float cb = btabH[t * 64 - q0];
#pragma unroll
      for (int kt = 0; kt < 4; ++kt)
#pragma unroll
        for (int r = 0; r < 4; ++r)
          pp[kt][r] = sc[kt][r] * SCL + cb;
    }

    // ---- lane-local max (tree) ----
    float mx[8];
#pragma unroll
    for (int i = 0; i < 8; ++i)
      mx[i] = fmaxf(pp[i >> 1][(i & 1) * 2], pp[i >> 1][(i & 1) * 2 + 1]);
    float m01 = fmaxf(mx[0], mx[1]), m23 = fmaxf(mx[2], mx[3]);
    float m45 = fmaxf(mx[4], mx[5]), m67 = fmaxf(mx[6], mx[7]);
    float tm = fmaxf(fmaxf(m01, m23), fmaxf(m45, m67));

    // ---- lazy row-max ----
    if (!__all(tm <= mrun + THR)) {
      tm = fmaxf(tm, __shfl_xor(tm, 16));
      tm = fmaxf(tm, __shfl_xor(tm, 32));
      float mn = fmaxf(mrun, tm);
      float sfv = exp2_raw(mrun - mn);
      mrun = mn;
      lpart *= sfv;
#pragma unroll
      for (int r = 0; r < 4; ++r) {
        float sq = __shfl(sfv, (lane & 48) | (lg * 4 + r));
#pragma unroll
        for (int db = 0; db < 4; ++db) ov[db][r] *= sq;
      }
    }

    // ---- exp2 + per-lane partial sum ----
#pragma unroll
    for (int kt = 0; kt < 4; ++kt)
#pragma unroll
      for (int r = 0; r < 4; ++r)
        pp[kt][r] = exp2_raw(pp[kt][r] - mrun);
    float s8[8];
#pragma unroll
    for (int i = 0; i < 8; ++i)
      s8[i] = pp[i >> 1][(i & 1) * 2] + pp[i >> 1][(i & 1) * 2 + 1];
    float s01 = s8[0] + s8[1], s23 = s8[2] + s8[3];
    float s45 = s8[4] + s8[5], s67 = s8[6] + s8[7];
    lpart += (s01 + s23) + (s45 + s67);

    // ---- pack P via v_cvt_pk_bf16_f32 ----
    union { bf16x8 v; unsigned u[4]; } pk[2];
#pragma unroll
    for (int kh = 0; kh < 2; ++kh) {
      asm("v_cvt_pk_bf16_f32 %0, %1, %2"
          : "=v"(pk[kh].u[0]) : "v"(pp[2 * kh][0]), "v"(pp[2 * kh][1]));
      asm("v_cvt_pk_bf16_f32 %0, %1, %2"
          : "=v"(pk[kh].u[1]) : "v"(pp[2 * kh][2]), "v"(pp[2 * kh][3]));
      asm("v_cvt_pk_bf16_f32 %0, %1, %2"
          : "=v"(pk[kh].u[2]) : "v"(pp[2 * kh + 1][0]), "v"(pp[2 * kh + 1][1]));
      asm("v_cvt_pk_bf16_f32 %0, %1, %2"
          : "=v"(pk[kh].u[3]) : "v"(pp[2 * kh + 1][2]), "v"(pp[2 * kh + 1][3]));
    }

    // ---- PV ----
    __builtin_amdgcn_s_setprio(1);
#pragma unroll
    for (int kh = 0; kh < 2; ++kh)
#pragma unroll
      for (int db = 0; db < 4; ++db)
        ov[db] = __builtin_amdgcn_mfma_f32_16x16x32_bf16(
            pk[kh].v, vfr[kh][db], ov[db], 0, 0, 0);
    __builtin_amdgcn_s_setprio(0);
  }

  // ---- epilogue ----
  float lsum = lpart;
  lsum += __shfl_xor(lsum, 16);
  lsum += __shfl_xor(lsum, 32);
  float invl = 1.0f / lsum;
#pragma unroll
  for (int r = 0; r < 4; ++r) {
    float iv = __shfl(invl, (lane & 48) | (lg * 4 + r));
    size_t row = (size_t)(bb * S_ + qw + lg * 4 + r);
#pragma unroll
    for (int db = 0; db < 4; ++db)
      ctxb[row * 1024 + h * 64 + db * 16 + lr] = f2bf(ov[db][r] * iv);
  }
}

extern "C" void kernel_launch(void* const* d_in, const int* in_sizes, int n_in,
                              void* d_out, int out_size, void* d_ws, size_t ws_size,
                              hipStream_t stream) {
  const float* hs      = (const float*)d_in[0];
  const float* w_qkv   = (const float*)d_in[1];
  const float* b_qkv   = (const float*)d_in[2];
  const float* w_dense = (const float*)d_in[3];
  const float* b_dense = (const float*)d_in[4];
  const float* rtab    = (const float*)d_in[5];
  float* out = (float*)d_out;

  char* ws = (char*)d_ws;
  unsigned short* qkvb = (unsigned short*)ws;                          // 24 MB
  unsigned short* ctxb = (unsigned short*)(ws + (((size_t)24) << 20)); // 8 MB
  unsigned short* hsb  = (unsigned short*)(ws + (((size_t)32) << 20)); // 8 MB
  unsigned short* wqT  = (unsigned short*)(ws + (((size_t)40) << 20)); // 6 MB
  unsigned short* wdT  = (unsigned short*)(ws + (((size_t)46) << 20)); // 2 MB
  unsigned short* vP   = (unsigned short*)(ws + (((size_t)48) << 20)); // 8 MB
  float* biasTab       = (float*)(ws + (((size_t)56) << 20));          // 256 KB

  hipLaunchKernelGGL(prologue_kernel, dim3(3328), dim3(256), 0, stream,
                     hs, hsb, w_qkv, wqT, w_dense, wdT, rtab, biasTab);
  hipLaunchKernelGGL((gemm_mfma_kernel<true>), dim3(24, 32), dim3(256), 0, stream,
                     hsb, wqT, b_qkv, (void*)qkvb, vP, 4096, 3072, 1024);
  hipLaunchKernelGGL(attn_mfma6_kernel, dim3(512), dim3(512), 0, stream,
                     qkvb, vP, biasTab, ctxb);
  hipLaunchKernelGGL((gemm_mfma64_kernel<false>), dim3(8, 64), dim3(256), 0, stream,
                     ctxb, wdT, b_dense, (void*)out, 4096, 1024, 1024);
}